// Round 1
// baseline (744.775 us; speedup 1.0000x reference)
//
#include <hip/hip_runtime.h>
#include <math.h>

#define B_   8
#define L_   2048
#define D_   1024
#define H_   2048
#define NBLK 16   // H_/128 N-blocks in the GEMM

typedef __bf16 bf16_t;
typedef bf16_t bf16x4_t __attribute__((ext_vector_type(4)));
typedef bf16_t bf16x8_t __attribute__((ext_vector_type(8)));
typedef float  f32x4_t  __attribute__((ext_vector_type(4)));

// ---------------------------------------------------------------------------
// K1: partial[m][nb] = sum_{j in nb's 128 cols} relu((hidden@W1)[m][j] + b1[j]) * W2[j]
// Split-bf16 GEMM: A = Ahi + Alo, B = Bhi + Blo; C ~= Ahi*Bhi + Ahi*Blo + Alo*Bhi
// 128x128 tile, BK=32, 4 waves (2x2), each wave 64x64 via 4x4 16x16x32 frags.
// ---------------------------------------------------------------------------
__global__ __launch_bounds__(256) void k1_gemm(
    const float* __restrict__ A,    // [16384][1024] hidden
    const float* __restrict__ W1,   // [1024][2048]
    const float* __restrict__ b1,   // [2048]
    const float* __restrict__ W2,   // [2048]
    float* __restrict__ partial)    // [16384][NBLK]
{
  __shared__ __align__(16) bf16_t sAhi[4][128][8];  // [kb][m][e]  k = kb*8+e
  __shared__ __align__(16) bf16_t sAlo[4][128][8];
  __shared__ __align__(16) bf16_t sBhi[4][128][8];  // [kb][n][e]  (B^T-style: k-contiguous per col)
  __shared__ __align__(16) bf16_t sBlo[4][128][8];
  __shared__ float part_lds[128][2];

  const int tid  = threadIdx.x;
  const int nb   = blockIdx.x;       // 0..15
  const int mb   = blockIdx.y;       // 0..127
  const int m0   = mb * 128;
  const int n0   = nb * 128;
  const int lane = tid & 63;
  const int wave = tid >> 6;
  const int wr = wave >> 1, wc = wave & 1;
  const int lr = lane & 15, lk = lane >> 4;

  f32x4_t acc[4][4];
#pragma unroll
  for (int m = 0; m < 4; ++m)
#pragma unroll
    for (int n = 0; n < 4; ++n)
      acc[m][n] = (f32x4_t){0.f, 0.f, 0.f, 0.f};

  for (int kk = 0; kk < 32; ++kk) {
    const int k0 = kk * 32;
    // ---- global loads (issued before barrier: overlap with prev MFMA) ----
    f32x4_t av[4];
    float   bx[4][4];
#pragma unroll
    for (int q = 0; q < 4; ++q) {
      const int flat = q * 256 + tid;          // 0..1023
      const int r    = flat >> 3;              // A row 0..127
      const int c4   = (flat & 7) << 2;        // A k-offset 0..28 step 4
      av[q] = *(const f32x4_t*)(A + (size_t)(m0 + r) * D_ + (k0 + c4));
      const int n  = flat & 127;               // B col 0..127
      const int kq = (flat >> 7) << 2;         // B k-offset 0..28 step 4
      const float* bp = W1 + (size_t)(k0 + kq) * H_ + (n0 + n);
      bx[q][0] = bp[0];
      bx[q][1] = bp[H_];
      bx[q][2] = bp[2 * H_];
      bx[q][3] = bp[3 * H_];
    }
    __syncthreads();   // prior iteration's ds_reads done before overwrite
    // ---- convert + ds_write ----
#pragma unroll
    for (int q = 0; q < 4; ++q) {
      const int flat = q * 256 + tid;
      {
        const int r  = flat >> 3;
        const int c4 = (flat & 7) << 2;
        const int kb = c4 >> 3, e = c4 & 7;    // e in {0,4}
        float x0 = av[q].x, x1 = av[q].y, x2 = av[q].z, x3 = av[q].w;
        bf16_t h0 = (bf16_t)x0, h1 = (bf16_t)x1, h2 = (bf16_t)x2, h3 = (bf16_t)x3;
        bf16x4_t hv = {h0, h1, h2, h3};
        bf16x4_t lv = {(bf16_t)(x0 - (float)h0), (bf16_t)(x1 - (float)h1),
                       (bf16_t)(x2 - (float)h2), (bf16_t)(x3 - (float)h3)};
        *(bf16x4_t*)&sAhi[kb][r][e] = hv;
        *(bf16x4_t*)&sAlo[kb][r][e] = lv;
      }
      {
        const int n  = flat & 127;
        const int kq = (flat >> 7) << 2;
        const int kb = kq >> 3, e = kq & 7;    // e in {0,4}
        float x0 = bx[q][0], x1 = bx[q][1], x2 = bx[q][2], x3 = bx[q][3];
        bf16_t h0 = (bf16_t)x0, h1 = (bf16_t)x1, h2 = (bf16_t)x2, h3 = (bf16_t)x3;
        bf16x4_t hv = {h0, h1, h2, h3};
        bf16x4_t lv = {(bf16_t)(x0 - (float)h0), (bf16_t)(x1 - (float)h1),
                       (bf16_t)(x2 - (float)h2), (bf16_t)(x3 - (float)h3)};
        *(bf16x4_t*)&sBhi[kb][n][e] = hv;
        *(bf16x4_t*)&sBlo[kb][n][e] = lv;
      }
    }
    __syncthreads();   // staged data visible
    // ---- fragments + MFMA ----
    bf16x8_t ahi[4], alo[4], bhi[4], blo[4];
#pragma unroll
    for (int m = 0; m < 4; ++m) {
      const int row = wr * 64 + m * 16 + lr;
      ahi[m] = *(const bf16x8_t*)&sAhi[lk][row][0];
      alo[m] = *(const bf16x8_t*)&sAlo[lk][row][0];
    }
#pragma unroll
    for (int n = 0; n < 4; ++n) {
      const int col = wc * 64 + n * 16 + lr;
      bhi[n] = *(const bf16x8_t*)&sBhi[lk][col][0];
      blo[n] = *(const bf16x8_t*)&sBlo[lk][col][0];
    }
#pragma unroll
    for (int m = 0; m < 4; ++m)
#pragma unroll
      for (int n = 0; n < 4; ++n) {
        acc[m][n] = __builtin_amdgcn_mfma_f32_16x16x32_bf16(ahi[m], bhi[n], acc[m][n], 0, 0, 0);
        acc[m][n] = __builtin_amdgcn_mfma_f32_16x16x32_bf16(ahi[m], blo[n], acc[m][n], 0, 0, 0);
        acc[m][n] = __builtin_amdgcn_mfma_f32_16x16x32_bf16(alo[m], bhi[n], acc[m][n], 0, 0, 0);
      }
  }

  // ---- epilogue: relu(C + b1) * W2, row-reduce, write partial ----
  float rs[4][4];
#pragma unroll
  for (int m = 0; m < 4; ++m)
#pragma unroll
    for (int rg = 0; rg < 4; ++rg) rs[m][rg] = 0.f;

#pragma unroll
  for (int n = 0; n < 4; ++n) {
    const int jg = n0 + wc * 64 + n * 16 + lr;   // D col = lane&15 (verified C/D map)
    const float w2v = W2[jg];
    const float b1v = b1[jg];
#pragma unroll
    for (int m = 0; m < 4; ++m)
#pragma unroll
      for (int rg = 0; rg < 4; ++rg) {
        float v = acc[m][n][rg] + b1v;
        rs[m][rg] += fmaxf(v, 0.f) * w2v;
      }
  }
#pragma unroll
  for (int m = 0; m < 4; ++m)
#pragma unroll
    for (int rg = 0; rg < 4; ++rg) {
      float v = rs[m][rg];
      v += __shfl_xor(v, 1);
      v += __shfl_xor(v, 2);
      v += __shfl_xor(v, 4);
      v += __shfl_xor(v, 8);
      rs[m][rg] = v;
    }
  __syncthreads();
  if (lr == 0) {
#pragma unroll
    for (int m = 0; m < 4; ++m)
#pragma unroll
      for (int rg = 0; rg < 4; ++rg)
        part_lds[wr * 64 + m * 16 + lk * 4 + rg][wc] = rs[m][rg];
  }
  __syncthreads();
  if (tid < 128) {
    const float sum = part_lds[tid][0] + part_lds[tid][1];
    partial[(size_t)(m0 + tid) * NBLK + nb] = sum;
  }
}

// ---------------------------------------------------------------------------
// K2: per-batch scan. length, hb (logit>0 & mask, forced boundary at last real
// token), exclusive cumsum -> segment starts, shortened mask, binomial NLL.
// ---------------------------------------------------------------------------
__global__ __launch_bounds__(256) void k2_scan(
    const float* __restrict__ partial,   // [16384][NBLK]
    const float* __restrict__ mask,      // [8][2048]
    const float* __restrict__ target,    // [8]
    const float* __restrict__ b2,        // [1]
    float* __restrict__ outmask,         // d_out + 16777219, [8][2048]
    int*   __restrict__ seg,             // [8][2050] segment starts + sentinel
    float* __restrict__ hdr)             // [8][4]: n, k, maxseg, -log_prob
{
  const int b = blockIdx.x, tid = threadIdx.x;
  __shared__ float redf[256];
  __shared__ int tsum[257];
  __shared__ unsigned char hbs[L_];

  // length
  float lm = 0.f;
#pragma unroll
  for (int e = 0; e < 8; ++e) lm += mask[b * L_ + tid * 8 + e];
  redf[tid] = lm;
  __syncthreads();
  for (int s = 128; s > 0; s >>= 1) {
    if (tid < s) redf[tid] += redf[tid + s];
    __syncthreads();
  }
  const int length = (int)(redf[0] + 0.5f);
  const float b2v = b2[0];

  // hb per token
  int hloc[8];
  int lsum = 0;
#pragma unroll
  for (int e = 0; e < 8; ++e) {
    const int t = tid * 8 + e;
    const float* pp = partial + (size_t)(b * L_ + t) * NBLK;
    float lg = b2v;
#pragma unroll
    for (int i = 0; i < NBLK; ++i) lg += pp[i];
    int hb = (lg > 0.f) && (t < length);
    if (length < L_ && t == length - 1) hb = 1;   // forced boundary at last real token
    hloc[e] = hb;
    hbs[t] = (unsigned char)hb;
    lsum += hb;
  }
  tsum[tid] = lsum;
  __syncthreads();
  if (tid == 0) {
    int run = 0;
    for (int i = 0; i < 256; ++i) { int v = tsum[i]; tsum[i] = run; run += v; }
    tsum[256] = run;
  }
  __syncthreads();
  const int ktot = tsum[256];

  // segment starts (segid increments by exactly 1 per boundary -> every
  // segment 0..maxseg is non-empty and contiguous among real tokens)
  int pre = tsum[tid];
  for (int e = 0; e < 8; ++e) {
    const int t = tid * 8 + e;
    if (t < length) {
      const bool st = (t == 0) || hbs[t - 1];
      if (st) seg[b * 2050 + pre] = t;           // pre == segid[t]
    }
    pre += hloc[e];
  }

  // shortened attention mask
#pragma unroll
  for (int e = 0; e < 8; ++e) {
    const int t = tid * 8 + e;
    outmask[b * L_ + t] = (t < ktot) ? 1.f : 0.f;
  }

  __syncthreads();
  if (tid == 0) {
    const int maxseg = ktot - (length > 0 ? (int)hbs[length - 1] : 0);
    seg[b * 2050 + maxseg + 1] = length;         // sentinel: end of last segment
    const float n = (float)length, k = (float)ktot;
    float p = target[b] / fmaxf(n, 1.f);
    p = fminf(fmaxf(p, 1e-6f), 1.f - 1e-6f);
    const float lp = lgammaf(n + 1.f) - lgammaf(k + 1.f) - lgammaf(n - k + 1.f)
                   + k * logf(p) + (n - k) * log1pf(-p);
    hdr[b * 4 + 0] = n;
    hdr[b * 4 + 1] = k;
    hdr[b * 4 + 2] = (float)maxseg;
    hdr[b * 4 + 3] = -lp;
  }
}

// ---------------------------------------------------------------------------
// K3: the three scalars
// ---------------------------------------------------------------------------
__global__ void k3_final(const float* __restrict__ hdr, float* __restrict__ out3)
{
  if (threadIdx.x == 0 && blockIdx.x == 0) {
    float s_lp = 0.f, s_k = 0.f, s_n = 0.f;
    for (int b = 0; b < B_; ++b) {
      s_n  += hdr[b * 4 + 0];
      s_k  += hdr[b * 4 + 1];
      s_lp += hdr[b * 4 + 3];
    }
    out3[0] = 10.f * (s_lp * 0.125f);  // loss = 10 * mean(-log_prob)
    out3[1] = s_k;                      // num_boundaries
    out3[2] = s_n;                      // total_positions
  }
}

// ---------------------------------------------------------------------------
// K4: pooled[b][s][:] = mean(hidden[b][start_s:end_s][:]) + PE[s][:]
// one block per (b, s); 256 threads x float4 = 1024 dims
// ---------------------------------------------------------------------------
__global__ __launch_bounds__(256) void k4_pool(
    const float* __restrict__ hidden,   // [8][2048][1024]
    const int*   __restrict__ seg,      // [8][2050]
    const float* __restrict__ hdr,      // [8][4]
    float* __restrict__ pooled)         // [8][2048][1024]
{
  const int bid = blockIdx.x;
  const int b = bid >> 11, s = bid & 2047;
  const int tid = threadIdx.x;
  const int maxseg = (int)hdr[b * 4 + 2];

  float a0 = 0.f, a1 = 0.f, a2 = 0.f, a3 = 0.f;
  if (s <= maxseg) {
    const int st = seg[b * 2050 + s];
    const int en = seg[b * 2050 + s + 1];
    const float* base = hidden + ((size_t)b * L_) * D_ + tid * 4;
    for (int t = st; t < en; ++t) {
      const f32x4_t v = *(const f32x4_t*)(base + (size_t)t * D_);
      a0 += v.x; a1 += v.y; a2 += v.z; a3 += v.w;
    }
    const float cnt = (float)(en - st);
    const float inv = 1.f / (cnt + 1e-9f);
    a0 *= inv; a1 *= inv; a2 *= inv; a3 *= inv;
  }
  // sinusoidal PE: dims 4t..4t+3 are pairs m0=2t (sin,cos), m1=2t+1 (sin,cos)
  const float e0 = (float)(4 * tid)     * (1.f / 1024.f);
  const float e1 = (float)(4 * tid + 2) * (1.f / 1024.f);
  const float ang0 = (float)s / powf(10000.f, e0);
  const float ang1 = (float)s / powf(10000.f, e1);
  float s0, c0, s1, c1;
  sincosf(ang0, &s0, &c0);
  sincosf(ang1, &s1, &c1);
  f32x4_t o;
  o.x = a0 + s0; o.y = a1 + c0; o.z = a2 + s1; o.w = a3 + c1;
  *(f32x4_t*)(pooled + ((size_t)(b * L_ + s)) * D_ + tid * 4) = o;
}

// ---------------------------------------------------------------------------
extern "C" void kernel_launch(void* const* d_in, const int* in_sizes, int n_in,
                              void* d_out, int out_size, void* d_ws, size_t ws_size,
                              hipStream_t stream)
{
  (void)in_sizes; (void)n_in; (void)out_size; (void)ws_size;
  const float* hidden = (const float*)d_in[0];
  const float* amask  = (const float*)d_in[1];
  const float* target = (const float*)d_in[2];
  const float* W1     = (const float*)d_in[3];
  const float* b1     = (const float*)d_in[4];
  const float* W2     = (const float*)d_in[5];
  const float* b2     = (const float*)d_in[6];

  float* out     = (float*)d_out;
  float* pooled  = out;                       // 16777216 floats
  float* out3    = out + 16777216;            // loss, num_boundaries, total_positions
  float* outmask = out + 16777219;            // 16384 floats

  float* partial = (float*)d_ws;                                        // 16384*16 f32 = 1 MB
  int*   seg     = (int*)((char*)d_ws + (size_t)16384 * 16 * 4);        // 8*2050 int
  float* hdr     = (float*)((char*)d_ws + (size_t)16384 * 16 * 4 + 8 * 2050 * 4);

  k1_gemm<<<dim3(16, 128), dim3(256), 0, stream>>>(hidden, W1, b1, W2, partial);
  k2_scan<<<dim3(8), dim3(256), 0, stream>>>(partial, amask, target, b2, outmask, seg, hdr);
  k3_final<<<dim3(1), dim3(64), 0, stream>>>(hdr, out3);
  k4_pool<<<dim3(16384), dim3(256), 0, stream>>>(hidden, seg, hdr, pooled);
}

// Round 2
// 303.473 us; speedup vs baseline: 2.4542x; 2.4542x over previous
//
#include <hip/hip_runtime.h>
#include <math.h>

#define B_   8
#define L_   2048
#define D_   1024
#define H_   2048
#define NBLK 16   // H_/128 N-blocks in the GEMM
#define CHK  32   // tokens per chunk in pooling pre-pass
#define NCH  (L_ / CHK)   // 64 chunks per batch item

typedef __bf16 bf16_t;
typedef bf16_t bf16x4_t __attribute__((ext_vector_type(4)));
typedef bf16_t bf16x8_t __attribute__((ext_vector_type(8)));
typedef float  f32x4_t  __attribute__((ext_vector_type(4)));

// ---------------------------------------------------------------------------
// K1: partial[m][nb] = sum_{j in nb's 128 cols} relu((hidden@W1)[m][j] + b1[j]) * W2[j]
// Split-bf16 GEMM: A = Ahi + Alo, B = Bhi + Blo; C ~= Ahi*Bhi + Ahi*Blo + Alo*Bhi
// 128x128 tile, BK=32, 4 waves (2x2), each wave 64x64 via 4x4 16x16x32 frags.
// ---------------------------------------------------------------------------
__global__ __launch_bounds__(256) void k1_gemm(
    const float* __restrict__ A,    // [16384][1024] hidden
    const float* __restrict__ W1,   // [1024][2048]
    const float* __restrict__ b1,   // [2048]
    const float* __restrict__ W2,   // [2048]
    float* __restrict__ partial)    // [16384][NBLK]
{
  __shared__ __align__(16) bf16_t sAhi[4][128][8];  // [kb][m][e]  k = kb*8+e
  __shared__ __align__(16) bf16_t sAlo[4][128][8];
  __shared__ __align__(16) bf16_t sBhi[4][128][8];  // [kb][n][e]  (B^T-style: k-contiguous per col)
  __shared__ __align__(16) bf16_t sBlo[4][128][8];
  __shared__ float part_lds[128][2];

  const int tid  = threadIdx.x;
  const int nb   = blockIdx.x;       // 0..15
  const int mb   = blockIdx.y;       // 0..127
  const int m0   = mb * 128;
  const int n0   = nb * 128;
  const int lane = tid & 63;
  const int wave = tid >> 6;
  const int wr = wave >> 1, wc = wave & 1;
  const int lr = lane & 15, lk = lane >> 4;

  f32x4_t acc[4][4];
#pragma unroll
  for (int m = 0; m < 4; ++m)
#pragma unroll
    for (int n = 0; n < 4; ++n)
      acc[m][n] = (f32x4_t){0.f, 0.f, 0.f, 0.f};

  for (int kk = 0; kk < 32; ++kk) {
    const int k0 = kk * 32;
    // ---- global loads (issued before barrier: overlap with prev MFMA) ----
    f32x4_t av[4];
    float   bx[4][4];
#pragma unroll
    for (int q = 0; q < 4; ++q) {
      const int flat = q * 256 + tid;          // 0..1023
      const int r    = flat >> 3;              // A row 0..127
      const int c4   = (flat & 7) << 2;        // A k-offset 0..28 step 4
      av[q] = *(const f32x4_t*)(A + (size_t)(m0 + r) * D_ + (k0 + c4));
      const int n  = flat & 127;               // B col 0..127
      const int kq = (flat >> 7) << 2;         // B k-offset 0..28 step 4
      const float* bp = W1 + (size_t)(k0 + kq) * H_ + (n0 + n);
      bx[q][0] = bp[0];
      bx[q][1] = bp[H_];
      bx[q][2] = bp[2 * H_];
      bx[q][3] = bp[3 * H_];
    }
    __syncthreads();   // prior iteration's ds_reads done before overwrite
    // ---- convert + ds_write ----
#pragma unroll
    for (int q = 0; q < 4; ++q) {
      const int flat = q * 256 + tid;
      {
        const int r  = flat >> 3;
        const int c4 = (flat & 7) << 2;
        const int kb = c4 >> 3, e = c4 & 7;    // e in {0,4}
        float x0 = av[q].x, x1 = av[q].y, x2 = av[q].z, x3 = av[q].w;
        bf16_t h0 = (bf16_t)x0, h1 = (bf16_t)x1, h2 = (bf16_t)x2, h3 = (bf16_t)x3;
        bf16x4_t hv = {h0, h1, h2, h3};
        bf16x4_t lv = {(bf16_t)(x0 - (float)h0), (bf16_t)(x1 - (float)h1),
                       (bf16_t)(x2 - (float)h2), (bf16_t)(x3 - (float)h3)};
        *(bf16x4_t*)&sAhi[kb][r][e] = hv;
        *(bf16x4_t*)&sAlo[kb][r][e] = lv;
      }
      {
        const int n  = flat & 127;
        const int kq = (flat >> 7) << 2;
        const int kb = kq >> 3, e = kq & 7;    // e in {0,4}
        float x0 = bx[q][0], x1 = bx[q][1], x2 = bx[q][2], x3 = bx[q][3];
        bf16_t h0 = (bf16_t)x0, h1 = (bf16_t)x1, h2 = (bf16_t)x2, h3 = (bf16_t)x3;
        bf16x4_t hv = {h0, h1, h2, h3};
        bf16x4_t lv = {(bf16_t)(x0 - (float)h0), (bf16_t)(x1 - (float)h1),
                       (bf16_t)(x2 - (float)h2), (bf16_t)(x3 - (float)h3)};
        *(bf16x4_t*)&sBhi[kb][n][e] = hv;
        *(bf16x4_t*)&sBlo[kb][n][e] = lv;
      }
    }
    __syncthreads();   // staged data visible
    // ---- fragments + MFMA ----
    bf16x8_t ahi[4], alo[4], bhi[4], blo[4];
#pragma unroll
    for (int m = 0; m < 4; ++m) {
      const int row = wr * 64 + m * 16 + lr;
      ahi[m] = *(const bf16x8_t*)&sAhi[lk][row][0];
      alo[m] = *(const bf16x8_t*)&sAlo[lk][row][0];
    }
#pragma unroll
    for (int n = 0; n < 4; ++n) {
      const int col = wc * 64 + n * 16 + lr;
      bhi[n] = *(const bf16x8_t*)&sBhi[lk][col][0];
      blo[n] = *(const bf16x8_t*)&sBlo[lk][col][0];
    }
#pragma unroll
    for (int m = 0; m < 4; ++m)
#pragma unroll
      for (int n = 0; n < 4; ++n) {
        acc[m][n] = __builtin_amdgcn_mfma_f32_16x16x32_bf16(ahi[m], bhi[n], acc[m][n], 0, 0, 0);
        acc[m][n] = __builtin_amdgcn_mfma_f32_16x16x32_bf16(ahi[m], blo[n], acc[m][n], 0, 0, 0);
        acc[m][n] = __builtin_amdgcn_mfma_f32_16x16x32_bf16(alo[m], bhi[n], acc[m][n], 0, 0, 0);
      }
  }

  // ---- epilogue: relu(C + b1) * W2, row-reduce, write partial ----
  float rs[4][4];
#pragma unroll
  for (int m = 0; m < 4; ++m)
#pragma unroll
    for (int rg = 0; rg < 4; ++rg) rs[m][rg] = 0.f;

#pragma unroll
  for (int n = 0; n < 4; ++n) {
    const int jg = n0 + wc * 64 + n * 16 + lr;   // D col = lane&15 (verified C/D map)
    const float w2v = W2[jg];
    const float b1v = b1[jg];
#pragma unroll
    for (int m = 0; m < 4; ++m)
#pragma unroll
      for (int rg = 0; rg < 4; ++rg) {
        float v = acc[m][n][rg] + b1v;
        rs[m][rg] += fmaxf(v, 0.f) * w2v;
      }
  }
#pragma unroll
  for (int m = 0; m < 4; ++m)
#pragma unroll
    for (int rg = 0; rg < 4; ++rg) {
      float v = rs[m][rg];
      v += __shfl_xor(v, 1);
      v += __shfl_xor(v, 2);
      v += __shfl_xor(v, 4);
      v += __shfl_xor(v, 8);
      rs[m][rg] = v;
    }
  __syncthreads();
  if (lr == 0) {
#pragma unroll
    for (int m = 0; m < 4; ++m)
#pragma unroll
      for (int rg = 0; rg < 4; ++rg)
        part_lds[wr * 64 + m * 16 + lk * 4 + rg][wc] = rs[m][rg];
  }
  __syncthreads();
  if (tid < 128) {
    const float sum = part_lds[tid][0] + part_lds[tid][1];
    partial[(size_t)(m0 + tid) * NBLK + nb] = sum;
  }
}

// ---------------------------------------------------------------------------
// K2: per-batch scan. length, hb (logit>0 & mask, forced boundary at last real
// token), exclusive cumsum -> segment starts, shortened mask, binomial NLL.
// ---------------------------------------------------------------------------
__global__ __launch_bounds__(256) void k2_scan(
    const float* __restrict__ partial,   // [16384][NBLK]
    const float* __restrict__ mask,      // [8][2048]
    const float* __restrict__ target,    // [8]
    const float* __restrict__ b2,        // [1]
    float* __restrict__ outmask,         // d_out + 16777219, [8][2048]
    int*   __restrict__ seg,             // [8][2050] segment starts + sentinel
    float* __restrict__ hdr)             // [8][4]: n, k, maxseg, -log_prob
{
  const int b = blockIdx.x, tid = threadIdx.x;
  __shared__ float redf[256];
  __shared__ int tsum[257];
  __shared__ unsigned char hbs[L_];

  // length
  float lm = 0.f;
#pragma unroll
  for (int e = 0; e < 8; ++e) lm += mask[b * L_ + tid * 8 + e];
  redf[tid] = lm;
  __syncthreads();
  for (int s = 128; s > 0; s >>= 1) {
    if (tid < s) redf[tid] += redf[tid + s];
    __syncthreads();
  }
  const int length = (int)(redf[0] + 0.5f);
  const float b2v = b2[0];

  // hb per token
  int hloc[8];
  int lsum = 0;
#pragma unroll
  for (int e = 0; e < 8; ++e) {
    const int t = tid * 8 + e;
    const float* pp = partial + (size_t)(b * L_ + t) * NBLK;
    float lg = b2v;
#pragma unroll
    for (int i = 0; i < NBLK; ++i) lg += pp[i];
    int hb = (lg > 0.f) && (t < length);
    if (length < L_ && t == length - 1) hb = 1;   // forced boundary at last real token
    hloc[e] = hb;
    hbs[t] = (unsigned char)hb;
    lsum += hb;
  }
  tsum[tid] = lsum;
  __syncthreads();
  if (tid == 0) {
    int run = 0;
    for (int i = 0; i < 256; ++i) { int v = tsum[i]; tsum[i] = run; run += v; }
    tsum[256] = run;
  }
  __syncthreads();
  const int ktot = tsum[256];

  // segment starts (segid increments by exactly 1 per boundary -> every
  // segment 0..maxseg is non-empty and contiguous among real tokens)
  int pre = tsum[tid];
  for (int e = 0; e < 8; ++e) {
    const int t = tid * 8 + e;
    if (t < length) {
      const bool st = (t == 0) || hbs[t - 1];
      if (st) seg[b * 2050 + pre] = t;           // pre == segid[t]
    }
    pre += hloc[e];
  }

  // shortened attention mask
#pragma unroll
  for (int e = 0; e < 8; ++e) {
    const int t = tid * 8 + e;
    outmask[b * L_ + t] = (t < ktot) ? 1.f : 0.f;
  }

  __syncthreads();
  if (tid == 0) {
    const int maxseg = ktot - (length > 0 ? (int)hbs[length - 1] : 0);
    seg[b * 2050 + maxseg + 1] = length;         // sentinel: end of last segment
    const float n = (float)length, k = (float)ktot;
    float p = target[b] / fmaxf(n, 1.f);
    p = fminf(fmaxf(p, 1e-6f), 1.f - 1e-6f);
    const float lp = lgammaf(n + 1.f) - lgammaf(k + 1.f) - lgammaf(n - k + 1.f)
                   + k * logf(p) + (n - k) * log1pf(-p);
    hdr[b * 4 + 0] = n;
    hdr[b * 4 + 1] = k;
    hdr[b * 4 + 2] = (float)maxseg;
    hdr[b * 4 + 3] = -lp;
  }
}

// ---------------------------------------------------------------------------
// K3: the three scalars
// ---------------------------------------------------------------------------
__global__ void k3_final(const float* __restrict__ hdr, float* __restrict__ out3)
{
  if (threadIdx.x == 0 && blockIdx.x == 0) {
    float s_lp = 0.f, s_k = 0.f, s_n = 0.f;
    for (int b = 0; b < B_; ++b) {
      s_n  += hdr[b * 4 + 0];
      s_k  += hdr[b * 4 + 1];
      s_lp += hdr[b * 4 + 3];
    }
    out3[0] = 10.f * (s_lp * 0.125f);  // loss = 10 * mean(-log_prob)
    out3[1] = s_k;                      // num_boundaries
    out3[2] = s_n;                      // total_positions
  }
}

// ---------------------------------------------------------------------------
// K4a: chunkSum[b][c][:] = sum of hidden rows in 32-token chunk c
// 512 blocks x 256 threads; fully parallel streaming read of hidden (64 MB).
// ---------------------------------------------------------------------------
__global__ __launch_bounds__(256) void k4a_chunksum(
    const float* __restrict__ hidden,    // [8][2048][1024]
    float* __restrict__ chunkSum)        // [8][NCH][1024]
{
  const int tc = blockIdx.x;     // 0..NCH-1
  const int b  = blockIdx.y;     // 0..7
  const int tid = threadIdx.x;
  const float* base = hidden + ((size_t)(b * L_ + tc * CHK)) * D_ + tid * 4;
  float a0 = 0.f, a1 = 0.f, a2 = 0.f, a3 = 0.f;
#pragma unroll 4
  for (int t = 0; t < CHK; ++t) {
    const f32x4_t v = *(const f32x4_t*)(base + (size_t)t * D_);
    a0 += v.x; a1 += v.y; a2 += v.z; a3 += v.w;
  }
  f32x4_t o = {a0, a1, a2, a3};
  *(f32x4_t*)(chunkSum + ((size_t)(b * NCH + tc)) * D_ + tid * 4) = o;
}

// ---------------------------------------------------------------------------
// K4b: pooled[b][s][:] = mean(hidden[b][st:en][:]) + PE[s][:]
// Segment mean = (edge-token rows) + (full 32-token chunk sums). Worst case
// per thread: ~62 edge rows + <=64 chunk vectors, vs up to 2048 rows before.
// ---------------------------------------------------------------------------
__global__ __launch_bounds__(256) void k4b_pool(
    const float* __restrict__ hidden,    // [8][2048][1024]
    const float* __restrict__ chunkSum,  // [8][NCH][1024]
    const int*   __restrict__ seg,       // [8][2050]
    const float* __restrict__ hdr,       // [8][4]
    float* __restrict__ pooled)          // [8][2048][1024]
{
  const int bid = blockIdx.x;
  const int b = bid >> 11, s = bid & 2047;
  const int tid = threadIdx.x;
  const int maxseg = (int)hdr[b * 4 + 2];

  float a0 = 0.f, a1 = 0.f, a2 = 0.f, a3 = 0.f;
  if (s <= maxseg) {
    const int st = seg[b * 2050 + s];
    const int en = seg[b * 2050 + s + 1];
    const float* hrow = hidden + (size_t)(b * L_) * D_ + tid * 4;
    const float* crow = chunkSum + (size_t)(b * NCH) * D_ + tid * 4;
    const int cs = (st + CHK - 1) / CHK;   // first full chunk
    const int ce = en / CHK;               // one past last full chunk
    if (cs >= ce) {
      for (int t = st; t < en; ++t) {
        const f32x4_t v = *(const f32x4_t*)(hrow + (size_t)t * D_);
        a0 += v.x; a1 += v.y; a2 += v.z; a3 += v.w;
      }
    } else {
      for (int t = st; t < cs * CHK; ++t) {
        const f32x4_t v = *(const f32x4_t*)(hrow + (size_t)t * D_);
        a0 += v.x; a1 += v.y; a2 += v.z; a3 += v.w;
      }
#pragma unroll 4
      for (int c = cs; c < ce; ++c) {
        const f32x4_t v = *(const f32x4_t*)(crow + (size_t)c * D_);
        a0 += v.x; a1 += v.y; a2 += v.z; a3 += v.w;
      }
      for (int t = ce * CHK; t < en; ++t) {
        const f32x4_t v = *(const f32x4_t*)(hrow + (size_t)t * D_);
        a0 += v.x; a1 += v.y; a2 += v.z; a3 += v.w;
      }
    }
    const float cnt = (float)(en - st);
    const float inv = 1.f / (cnt + 1e-9f);
    a0 *= inv; a1 *= inv; a2 *= inv; a3 *= inv;
  }
  // sinusoidal PE: dims 4t..4t+3 are pairs m0=2t (sin,cos), m1=2t+1 (sin,cos)
  const float e0 = (float)(4 * tid)     * (1.f / 1024.f);
  const float e1 = (float)(4 * tid + 2) * (1.f / 1024.f);
  const float ang0 = (float)s / powf(10000.f, e0);
  const float ang1 = (float)s / powf(10000.f, e1);
  float s0, c0, s1, c1;
  sincosf(ang0, &s0, &c0);
  sincosf(ang1, &s1, &c1);
  f32x4_t o;
  o.x = a0 + s0; o.y = a1 + c0; o.z = a2 + s1; o.w = a3 + c1;
  *(f32x4_t*)(pooled + ((size_t)(b * L_ + s)) * D_ + tid * 4) = o;
}

// ---------------------------------------------------------------------------
extern "C" void kernel_launch(void* const* d_in, const int* in_sizes, int n_in,
                              void* d_out, int out_size, void* d_ws, size_t ws_size,
                              hipStream_t stream)
{
  (void)in_sizes; (void)n_in; (void)out_size; (void)ws_size;
  const float* hidden = (const float*)d_in[0];
  const float* amask  = (const float*)d_in[1];
  const float* target = (const float*)d_in[2];
  const float* W1     = (const float*)d_in[3];
  const float* b1     = (const float*)d_in[4];
  const float* W2     = (const float*)d_in[5];
  const float* b2     = (const float*)d_in[6];

  float* out     = (float*)d_out;
  float* pooled  = out;                       // 16777216 floats
  float* out3    = out + 16777216;            // loss, num_boundaries, total_positions
  float* outmask = out + 16777219;            // 16384 floats

  char* ws = (char*)d_ws;
  float* partial  = (float*)ws;                                  // 16384*16*4 = 1 MB
  ws += (size_t)16384 * NBLK * 4;
  int*   seg      = (int*)ws;                                    // 8*2050*4
  ws += (size_t)B_ * 2050 * 4;
  float* hdr      = (float*)ws;                                  // 8*4*4
  ws += (size_t)B_ * 4 * 4;
  float* chunkSum = (float*)ws;                                  // 8*64*1024*4 = 2 MB

  k1_gemm<<<dim3(16, 128), dim3(256), 0, stream>>>(hidden, W1, b1, W2, partial);
  k2_scan<<<dim3(8), dim3(256), 0, stream>>>(partial, amask, target, b2, outmask, seg, hdr);
  k3_final<<<dim3(1), dim3(64), 0, stream>>>(hdr, out3);
  k4a_chunksum<<<dim3(NCH, B_), dim3(256), 0, stream>>>(hidden, chunkSum);
  k4b_pool<<<dim3(16384), dim3(256), 0, stream>>>(hidden, chunkSum, seg, hdr, pooled);
}

// Round 3
// 176.989 us; speedup vs baseline: 4.2080x; 1.7146x over previous
//
#include <hip/hip_runtime.h>
#include <math.h>

#define B_   8
#define L_   2048
#define D_   1024
#define H_   2048
#define NBLK 16            // H_/128 N-blocks in the GEMM
#define CHK  32            // tokens per chunk in pooling pre-pass
#define NCH  (L_ / CHK)    // 64 chunks per batch item
#define BK   64
#define NK   (D_ / BK)     // 16 K-steps
#define MARGIN  0.05f      // |logit| below this -> exact f32 recompute
#define MAXFLAG 1024

typedef __bf16 bf16_t;
typedef bf16_t bf16x8_t __attribute__((ext_vector_type(8)));
typedef float  f32x4_t  __attribute__((ext_vector_type(4)));

// ---------------------------------------------------------------------------
// K0a: hidden f32 -> Abf bf16, tiled+swizzled to the exact k1 LDS image:
// tile (mb,kk) = 16KB: [r 0..127][chunk (kb ^ (r&7)) 0..7][8 elems]
// ---------------------------------------------------------------------------
__global__ __launch_bounds__(256) void k0a_splitA(
    const float* __restrict__ A,      // [16384][1024]
    bf16_t* __restrict__ Abf)         // [128 mb][16 kk] tiles of 16KB
{
  const int kk = blockIdx.x;   // 0..15
  const int mb = blockIdx.y;   // 0..127
  const int tid = threadIdx.x;
  const int r = tid >> 1, h = tid & 1;
  const float* src = A + (size_t)(mb * 128 + r) * D_ + kk * BK + h * 32;
  float v[32];
#pragma unroll
  for (int q = 0; q < 8; ++q) {
    f32x4_t x = *(const f32x4_t*)(src + q * 4);
    v[q*4] = x.x; v[q*4+1] = x.y; v[q*4+2] = x.z; v[q*4+3] = x.w;
  }
  char* dst = (char*)Abf + ((size_t)(mb * 16 + kk)) * 16384 + r * 128;
#pragma unroll
  for (int j = 0; j < 4; ++j) {
    bf16x8_t o;
#pragma unroll
    for (int e = 0; e < 8; ++e) o[e] = (bf16_t)v[j * 8 + e];
    const int kb = h * 4 + j;
    *(bf16x8_t*)(dst + ((kb ^ (r & 7)) << 4)) = o;
  }
}

// ---------------------------------------------------------------------------
// K0b: W1 f32 -> Bbf bf16, tile (nb,kk) = 16KB: [c][chunk (kb ^ (c&7))][8]
// ---------------------------------------------------------------------------
__global__ __launch_bounds__(256) void k0b_splitB(
    const float* __restrict__ W1,     // [1024][2048]
    bf16_t* __restrict__ Bbf)         // [16 nb][16 kk] tiles of 16KB
{
  const int kk = blockIdx.x;   // 0..15
  const int nb = blockIdx.y;   // 0..15
  const int tid = threadIdx.x;
  const int c = tid >> 1, h = tid & 1;
  const float* src = W1 + (size_t)(kk * BK + h * 32) * H_ + nb * 128 + c;
  float v[32];
#pragma unroll
  for (int j = 0; j < 32; ++j) v[j] = src[(size_t)j * H_];
  char* dst = (char*)Bbf + ((size_t)(nb * 16 + kk)) * 16384 + c * 128;
#pragma unroll
  for (int j = 0; j < 4; ++j) {
    bf16x8_t o;
#pragma unroll
    for (int e = 0; e < 8; ++e) o[e] = (bf16_t)v[j * 8 + e];
    const int kb = h * 4 + j;
    *(bf16x8_t*)(dst + ((kb ^ (c & 7)) << 4)) = o;
  }
}

// ---------------------------------------------------------------------------
// K1: bf16 GEMM, 128x128 tile, BK=64, 4 waves (2x2, wave tile 64x64).
// global_load_lds(16B) staging of pre-swizzled tiles, double-buffered,
// one barrier per K-step. Epilogue: relu(C + b1) . W2 -> partial[m][nb].
// ---------------------------------------------------------------------------
__global__ __launch_bounds__(256, 2) void k1_gemm(
    const bf16_t* __restrict__ Abf,
    const bf16_t* __restrict__ Bbf,
    const float* __restrict__ b1,
    const float* __restrict__ W2,
    float* __restrict__ partial)    // [16384][NBLK]
{
  __shared__ __align__(16) unsigned char smem[65536];  // 2 x (A 16KB | B 16KB)

  const int tid  = threadIdx.x;
  const int nb   = blockIdx.x;       // 0..15
  const int mb   = blockIdx.y;       // 0..127
  const int m0   = mb * 128;
  const int n0   = nb * 128;
  const int lane = tid & 63;
  const int wave = tid >> 6;
  const int wr = wave >> 1, wc = wave & 1;
  const int lr = lane & 15, lk = lane >> 4;

  const char* aT = (const char*)Abf + ((size_t)mb * 16) * 16384;
  const char* bT = (const char*)Bbf + ((size_t)nb * 16) * 16384;

  f32x4_t acc[4][4];
#pragma unroll
  for (int m = 0; m < 4; ++m)
#pragma unroll
    for (int n = 0; n < 4; ++n)
      acc[m][n] = (f32x4_t){0.f, 0.f, 0.f, 0.f};

  // stage K-step kk into buffer buf (32 x 1KB chunks; wave w does w*8..w*8+7)
  auto stage = [&](int kk, int buf) {
    unsigned char* ldsb = smem + buf * 32768;
#pragma unroll
    for (int j = 0; j < 8; ++j) {
      const int i = wave * 8 + j;
      const char* g = (i < 16 ? aT + (size_t)kk * 16384 + i * 1024
                              : bT + (size_t)kk * 16384 + (i - 16) * 1024)
                      + lane * 16;
      __builtin_amdgcn_global_load_lds(
          (const __attribute__((address_space(1))) void*)g,
          (__attribute__((address_space(3))) void*)(ldsb + i * 1024),
          16, 0, 0);
    }
  };

  stage(0, 0);
  for (int kk = 0; kk < NK; ++kk) {
    __syncthreads();   // staged(kk) visible; buf[(kk+1)&1] free to overwrite
    if (kk + 1 < NK) stage(kk + 1, (kk + 1) & 1);
    const unsigned char* sA = smem + (kk & 1) * 32768;
    const unsigned char* sB = sA + 16384;
#pragma unroll
    for (int g = 0; g < 2; ++g) {
      bf16x8_t a[4], b[4];
#pragma unroll
      for (int m = 0; m < 4; ++m) {
        const int r = wr * 64 + m * 16 + lr;
        a[m] = *(const bf16x8_t*)(sA + r * 128 + (((g * 4 + lk) ^ (r & 7)) << 4));
      }
#pragma unroll
      for (int n = 0; n < 4; ++n) {
        const int c = wc * 64 + n * 16 + lr;
        b[n] = *(const bf16x8_t*)(sB + c * 128 + (((g * 4 + lk) ^ (c & 7)) << 4));
      }
#pragma unroll
      for (int m = 0; m < 4; ++m)
#pragma unroll
        for (int n = 0; n < 4; ++n)
          acc[m][n] = __builtin_amdgcn_mfma_f32_16x16x32_bf16(a[m], b[n], acc[m][n], 0, 0, 0);
    }
  }

  // ---- epilogue: relu(C + b1) * W2, row-reduce, write partial ----
  float rs[4][4];
#pragma unroll
  for (int m = 0; m < 4; ++m)
#pragma unroll
    for (int rg = 0; rg < 4; ++rg) rs[m][rg] = 0.f;

#pragma unroll
  for (int n = 0; n < 4; ++n) {
    const int jg = n0 + wc * 64 + n * 16 + lr;   // D col = lane&15 (validated map)
    const float w2v = W2[jg];
    const float b1v = b1[jg];
#pragma unroll
    for (int m = 0; m < 4; ++m)
#pragma unroll
      for (int rg = 0; rg < 4; ++rg) {
        float v = acc[m][n][rg] + b1v;
        rs[m][rg] += fmaxf(v, 0.f) * w2v;
      }
  }
#pragma unroll
  for (int m = 0; m < 4; ++m)
#pragma unroll
    for (int rg = 0; rg < 4; ++rg) {
      float v = rs[m][rg];
      v += __shfl_xor(v, 1);
      v += __shfl_xor(v, 2);
      v += __shfl_xor(v, 4);
      v += __shfl_xor(v, 8);
      rs[m][rg] = v;
    }
  __syncthreads();
  float (*part_lds)[2] = (float(*)[2])smem;   // alias (frag reads all done)
  if (lr == 0) {
#pragma unroll
    for (int m = 0; m < 4; ++m)
#pragma unroll
      for (int rg = 0; rg < 4; ++rg)
        part_lds[wr * 64 + m * 16 + lk * 4 + rg][wc] = rs[m][rg];
  }
  __syncthreads();
  if (tid < 128) {
    const float sum = part_lds[tid][0] + part_lds[tid][1];
    partial[(size_t)(m0 + tid) * NBLK + nb] = sum;
  }
}

// ---------------------------------------------------------------------------
// K2a: logits[i] = b2 + sum(partial[i][:]); flag near-threshold tokens
// ---------------------------------------------------------------------------
__global__ __launch_bounds__(256) void k2a_logits(
    const float* __restrict__ partial,
    const float* __restrict__ b2,
    float* __restrict__ logits,
    int* __restrict__ flaglist,
    int* __restrict__ flagcnt)
{
  const int i = blockIdx.x * 256 + threadIdx.x;   // 0..16383
  const float* pp = partial + (size_t)i * NBLK;
  float lg = b2[0];
#pragma unroll
  for (int j = 0; j < NBLK; ++j) lg += pp[j];
  logits[i] = lg;
  if (fabsf(lg) < MARGIN) {
    int s = atomicAdd(flagcnt, 1);
    if (s < MAXFLAG) flaglist[s] = i;
  }
}

// ---------------------------------------------------------------------------
// K2b: exact f32 recompute of flagged rows (one block per flagged token)
// ---------------------------------------------------------------------------
__global__ __launch_bounds__(256) void k2b_fixup(
    const float* __restrict__ hidden,
    const float* __restrict__ W1,
    const float* __restrict__ b1,
    const float* __restrict__ W2,
    const float* __restrict__ b2,
    const int* __restrict__ flaglist,
    const int* __restrict__ flagcnt,
    float* __restrict__ logits)
{
  const int cnt = min(*flagcnt, MAXFLAG);
  if ((int)blockIdx.x >= cnt) return;
  __shared__ float hrow[D_];
  __shared__ float red[256];
  const int i = flaglist[blockIdx.x];
  const int tid = threadIdx.x;
  const float* h = hidden + (size_t)i * D_;
  *(f32x4_t*)&hrow[tid * 4] = *(const f32x4_t*)&h[tid * 4];
  __syncthreads();
  float acc8[8];
#pragma unroll
  for (int cc = 0; cc < 8; ++cc) acc8[cc] = 0.f;
  for (int k = 0; k < D_; ++k) {
    const float hv = hrow[k];
    const float* wrow = W1 + (size_t)k * H_;
#pragma unroll
    for (int cc = 0; cc < 8; ++cc)
      acc8[cc] = fmaf(hv, wrow[cc * 256 + tid], acc8[cc]);
  }
  float s = 0.f;
#pragma unroll
  for (int cc = 0; cc < 8; ++cc) {
    const int col = cc * 256 + tid;
    s += fmaxf(acc8[cc] + b1[col], 0.f) * W2[col];
  }
  red[tid] = s;
  __syncthreads();
  for (int st = 128; st > 0; st >>= 1) {
    if (tid < st) red[tid] += red[tid + st];
    __syncthreads();
  }
  if (tid == 0) logits[i] = red[0] + b2[0];
}

// ---------------------------------------------------------------------------
// K2c: per-batch scan (unchanged logic, reads corrected logits)
// ---------------------------------------------------------------------------
__global__ __launch_bounds__(256) void k2c_scan(
    const float* __restrict__ logits,    // [8][2048]
    const float* __restrict__ mask,      // [8][2048]
    const float* __restrict__ target,    // [8]
    float* __restrict__ outmask,         // [8][2048]
    int*   __restrict__ seg,             // [8][2050]
    float* __restrict__ hdr)             // [8][4]
{
  const int b = blockIdx.x, tid = threadIdx.x;
  __shared__ float redf[256];
  __shared__ int tsum[257];
  __shared__ unsigned char hbs[L_];

  float lm = 0.f;
#pragma unroll
  for (int e = 0; e < 8; ++e) lm += mask[b * L_ + tid * 8 + e];
  redf[tid] = lm;
  __syncthreads();
  for (int s = 128; s > 0; s >>= 1) {
    if (tid < s) redf[tid] += redf[tid + s];
    __syncthreads();
  }
  const int length = (int)(redf[0] + 0.5f);

  int hloc[8];
  int lsum = 0;
#pragma unroll
  for (int e = 0; e < 8; ++e) {
    const int t = tid * 8 + e;
    const float lg = logits[b * L_ + t];
    int hb = (lg > 0.f) && (t < length);
    if (length < L_ && t == length - 1) hb = 1;
    hloc[e] = hb;
    hbs[t] = (unsigned char)hb;
    lsum += hb;
  }
  tsum[tid] = lsum;
  __syncthreads();
  if (tid == 0) {
    int run = 0;
    for (int i = 0; i < 256; ++i) { int v = tsum[i]; tsum[i] = run; run += v; }
    tsum[256] = run;
  }
  __syncthreads();
  const int ktot = tsum[256];

  int pre = tsum[tid];
  for (int e = 0; e < 8; ++e) {
    const int t = tid * 8 + e;
    if (t < length) {
      const bool st = (t == 0) || hbs[t - 1];
      if (st) seg[b * 2050 + pre] = t;
    }
    pre += hloc[e];
  }

#pragma unroll
  for (int e = 0; e < 8; ++e) {
    const int t = tid * 8 + e;
    outmask[b * L_ + t] = (t < ktot) ? 1.f : 0.f;
  }

  __syncthreads();
  if (tid == 0) {
    const int maxseg = ktot - (length > 0 ? (int)hbs[length - 1] : 0);
    seg[b * 2050 + maxseg + 1] = length;
    const float n = (float)length, k = (float)ktot;
    float p = target[b] / fmaxf(n, 1.f);
    p = fminf(fmaxf(p, 1e-6f), 1.f - 1e-6f);
    const float lp = lgammaf(n + 1.f) - lgammaf(k + 1.f) - lgammaf(n - k + 1.f)
                   + k * logf(p) + (n - k) * log1pf(-p);
    hdr[b * 4 + 0] = n;
    hdr[b * 4 + 1] = k;
    hdr[b * 4 + 2] = (float)maxseg;
    hdr[b * 4 + 3] = -lp;
  }
}

// ---------------------------------------------------------------------------
// K3: the three scalars
// ---------------------------------------------------------------------------
__global__ void k3_final(const float* __restrict__ hdr, float* __restrict__ out3)
{
  if (threadIdx.x == 0 && blockIdx.x == 0) {
    float s_lp = 0.f, s_k = 0.f, s_n = 0.f;
    for (int b = 0; b < B_; ++b) {
      s_n  += hdr[b * 4 + 0];
      s_k  += hdr[b * 4 + 1];
      s_lp += hdr[b * 4 + 3];
    }
    out3[0] = 10.f * (s_lp * 0.125f);
    out3[1] = s_k;
    out3[2] = s_n;
  }
}

// ---------------------------------------------------------------------------
// K4a: 32-token chunk sums of hidden
// ---------------------------------------------------------------------------
__global__ __launch_bounds__(256) void k4a_chunksum(
    const float* __restrict__ hidden,
    float* __restrict__ chunkSum)        // [8][NCH][1024]
{
  const int tc = blockIdx.x;
  const int b  = blockIdx.y;
  const int tid = threadIdx.x;
  const float* base = hidden + ((size_t)(b * L_ + tc * CHK)) * D_ + tid * 4;
  float a0 = 0.f, a1 = 0.f, a2 = 0.f, a3 = 0.f;
#pragma unroll 4
  for (int t = 0; t < CHK; ++t) {
    const f32x4_t v = *(const f32x4_t*)(base + (size_t)t * D_);
    a0 += v.x; a1 += v.y; a2 += v.z; a3 += v.w;
  }
  f32x4_t o = {a0, a1, a2, a3};
  *(f32x4_t*)(chunkSum + ((size_t)(b * NCH + tc)) * D_ + tid * 4) = o;
}

// ---------------------------------------------------------------------------
// K4b: pooled[b][s][:] = mean(hidden[b][st:en][:]) + PE[s][:]
// ---------------------------------------------------------------------------
__global__ __launch_bounds__(256) void k4b_pool(
    const float* __restrict__ hidden,
    const float* __restrict__ chunkSum,
    const int*   __restrict__ seg,
    const float* __restrict__ hdr,
    float* __restrict__ pooled)
{
  const int bid = blockIdx.x;
  const int b = bid >> 11, s = bid & 2047;
  const int tid = threadIdx.x;
  const int maxseg = (int)hdr[b * 4 + 2];

  float a0 = 0.f, a1 = 0.f, a2 = 0.f, a3 = 0.f;
  if (s <= maxseg) {
    const int st = seg[b * 2050 + s];
    const int en = seg[b * 2050 + s + 1];
    const float* hrow = hidden + (size_t)(b * L_) * D_ + tid * 4;
    const float* crow = chunkSum + (size_t)(b * NCH) * D_ + tid * 4;
    const int cs = (st + CHK - 1) / CHK;
    const int ce = en / CHK;
    if (cs >= ce) {
      for (int t = st; t < en; ++t) {
        const f32x4_t v = *(const f32x4_t*)(hrow + (size_t)t * D_);
        a0 += v.x; a1 += v.y; a2 += v.z; a3 += v.w;
      }
    } else {
      for (int t = st; t < cs * CHK; ++t) {
        const f32x4_t v = *(const f32x4_t*)(hrow + (size_t)t * D_);
        a0 += v.x; a1 += v.y; a2 += v.z; a3 += v.w;
      }
#pragma unroll 4
      for (int c = cs; c < ce; ++c) {
        const f32x4_t v = *(const f32x4_t*)(crow + (size_t)c * D_);
        a0 += v.x; a1 += v.y; a2 += v.z; a3 += v.w;
      }
      for (int t = ce * CHK; t < en; ++t) {
        const f32x4_t v = *(const f32x4_t*)(hrow + (size_t)t * D_);
        a0 += v.x; a1 += v.y; a2 += v.z; a3 += v.w;
      }
    }
    const float cnt = (float)(en - st);
    const float inv = 1.f / (cnt + 1e-9f);
    a0 *= inv; a1 *= inv; a2 *= inv; a3 *= inv;
  }
  const float e0 = (float)(4 * tid)     * (1.f / 1024.f);
  const float e1 = (float)(4 * tid + 2) * (1.f / 1024.f);
  const float ang0 = (float)s / powf(10000.f, e0);
  const float ang1 = (float)s / powf(10000.f, e1);
  float s0, c0, s1, c1;
  sincosf(ang0, &s0, &c0);
  sincosf(ang1, &s1, &c1);
  f32x4_t o;
  o.x = a0 + s0; o.y = a1 + c0; o.z = a2 + s1; o.w = a3 + c1;
  *(f32x4_t*)(pooled + ((size_t)(b * L_ + s)) * D_ + tid * 4) = o;
}

// ---------------------------------------------------------------------------
extern "C" void kernel_launch(void* const* d_in, const int* in_sizes, int n_in,
                              void* d_out, int out_size, void* d_ws, size_t ws_size,
                              hipStream_t stream)
{
  (void)in_sizes; (void)n_in; (void)out_size; (void)ws_size;
  const float* hidden = (const float*)d_in[0];
  const float* amask  = (const float*)d_in[1];
  const float* target = (const float*)d_in[2];
  const float* W1     = (const float*)d_in[3];
  const float* b1     = (const float*)d_in[4];
  const float* W2     = (const float*)d_in[5];
  const float* b2     = (const float*)d_in[6];

  float* out     = (float*)d_out;
  float* pooled  = out;                       // 16777216 floats (written LAST)
  float* out3    = out + 16777216;
  float* outmask = out + 16777219;

  // Abf (32MB) + Bbf (4MB) live inside the pooled output region as scratch;
  // k4b fully overwrites pooled afterwards.
  bf16_t* Abf = (bf16_t*)out;                       // 32 MB
  bf16_t* Bbf = (bf16_t*)(out + 8388608);           // 4 MB at byte offset 32MB

  char* ws = (char*)d_ws;
  float* partial  = (float*)ws;                      ws += (size_t)16384 * NBLK * 4;   // 1 MB
  int*   seg      = (int*)ws;                        ws += (size_t)B_ * 2050 * 4;
  float* hdr      = (float*)ws;                      ws += (size_t)B_ * 4 * 4;
  float* logits   = (float*)ws;                      ws += (size_t)B_ * L_ * 4;        // 64 KB
  int*   flaglist = (int*)ws;                        ws += (size_t)MAXFLAG * 4;
  int*   flagcnt  = (int*)ws;                        ws += 256;
  float* chunkSum = (float*)ws;                      // 2 MB

  hipMemsetAsync(flagcnt, 0, 4, stream);
  k0a_splitA<<<dim3(16, 128), dim3(256), 0, stream>>>(hidden, Abf);
  k0b_splitB<<<dim3(16, 16), dim3(256), 0, stream>>>(W1, Bbf);
  k1_gemm<<<dim3(16, 128), dim3(256), 0, stream>>>(Abf, Bbf, b1, W2, partial);
  k2a_logits<<<dim3(64), dim3(256), 0, stream>>>(partial, b2, logits, flaglist, flagcnt);
  k2b_fixup<<<dim3(MAXFLAG), dim3(256), 0, stream>>>(hidden, W1, b1, W2, b2,
                                                     flaglist, flagcnt, logits);
  k2c_scan<<<dim3(8), dim3(256), 0, stream>>>(logits, amask, target, outmask, seg, hdr);
  k3_final<<<dim3(1), dim3(64), 0, stream>>>(hdr, out3);
  k4a_chunksum<<<dim3(NCH, B_), dim3(256), 0, stream>>>(hidden, chunkSum);
  k4b_pool<<<dim3(16384), dim3(256), 0, stream>>>(hidden, chunkSum, seg, hdr, pooled);
}

// Round 4
// 148.375 us; speedup vs baseline: 5.0195x; 1.1928x over previous
//
#include <hip/hip_runtime.h>
#include <math.h>

#define B_   8
#define L_   2048
#define D_   1024
#define H_   2048
#define NBLK 8             // H_/256 N-tiles in the GEMM
#define CHK  32            // tokens per chunk in pooling pre-pass
#define NCH  (L_ / CHK)    // 64 chunks per batch item
#define BK   32
#define NK   (D_ / BK)     // 32 K-steps
#define MARGIN  0.05f      // |logit| below this -> exact f32 recompute
#define MAXFLAG 1024

typedef __bf16 bf16_t;
typedef bf16_t bf16x8_t __attribute__((ext_vector_type(8)));
typedef float  f32x4_t  __attribute__((ext_vector_type(4)));

// Swizzled tile images: tile = 256 rows x BK(32) k-elems bf16 = 16KB.
// Row r holds 4 chunks of 16B (8 bf16); k-group g stored at physical chunk
// g ^ ((r>>1)&3)  -> ds_read_b128 spans all 8 bank-quads over 8 rows (2-way).
#define TILE_BYTES 16384

// ---------------------------------------------------------------------------
// K0a (fused): hidden f32 -> Abf bf16 swizzled tiles  AND  32-token chunk sums
// grid (kk=32, mt=64), 256 threads; each thread owns one row's 32-k slab.
// ---------------------------------------------------------------------------
__global__ __launch_bounds__(256) void k0a_packA(
    const float* __restrict__ A,      // [16384][1024]
    bf16_t* __restrict__ Abf,         // [64 mt][32 kk] tiles of 16KB
    float* __restrict__ chunkSum)     // [8][NCH][1024]
{
  __shared__ float scratch[256][32];
  const int kk = blockIdx.x;   // 0..31
  const int mt = blockIdx.y;   // 0..63
  const int r  = threadIdx.x;  // 0..255
  const float* src = A + (size_t)(mt * 256 + r) * D_ + kk * BK;
  float v[32];
#pragma unroll
  for (int q = 0; q < 8; ++q) {
    f32x4_t x = *(const f32x4_t*)(src + q * 4);
    v[q*4] = x.x; v[q*4+1] = x.y; v[q*4+2] = x.z; v[q*4+3] = x.w;
  }
  char* dst = (char*)Abf + ((size_t)(mt * 32 + kk)) * TILE_BYTES + r * 64;
#pragma unroll
  for (int g = 0; g < 4; ++g) {
    bf16x8_t o;
#pragma unroll
    for (int e = 0; e < 8; ++e) o[e] = (bf16_t)v[g * 8 + e];
    *(bf16x8_t*)(dst + ((g ^ ((r >> 1) & 3)) << 4)) = o;
  }
  // chunk sums (32-token groups; mt spans 256 tokens = 8 chunks, batch-aligned)
#pragma unroll
  for (int j = 0; j < 32; ++j) scratch[r][j] = v[j];
  __syncthreads();
  const int ch = r >> 5, j = r & 31;
  float s = 0.f;
#pragma unroll
  for (int q = 0; q < 32; ++q) s += scratch[ch * 32 + q][j];
  const int b  = mt >> 3;
  const int cg = (mt & 7) * 8 + ch;
  chunkSum[((size_t)(b * NCH + cg)) * D_ + kk * 32 + j] = s;
}

// ---------------------------------------------------------------------------
// K0b: W1 f32 -> Bbf bf16 swizzled tiles (k-contiguous per column)
// ---------------------------------------------------------------------------
__global__ __launch_bounds__(256) void k0b_packB(
    const float* __restrict__ W1,     // [1024][2048]
    bf16_t* __restrict__ Bbf)         // [8 nt][32 kk] tiles of 16KB
{
  const int kk = blockIdx.x;   // 0..31
  const int nt = blockIdx.y;   // 0..7
  const int c  = threadIdx.x;  // 0..255 col within tile
  const float* src = W1 + (size_t)(kk * BK) * H_ + nt * 256 + c;
  float v[32];
#pragma unroll
  for (int j = 0; j < 32; ++j) v[j] = src[(size_t)j * H_];
  char* dst = (char*)Bbf + ((size_t)(nt * 32 + kk)) * TILE_BYTES + c * 64;
#pragma unroll
  for (int g = 0; g < 4; ++g) {
    bf16x8_t o;
#pragma unroll
    for (int e = 0; e < 8; ++e) o[e] = (bf16_t)v[g * 8 + e];
    *(bf16x8_t*)(dst + ((g ^ ((c >> 1) & 3)) << 4)) = o;
  }
}

// ---------------------------------------------------------------------------
// K1: bf16 GEMM 256x256 tile, BK=32, 8 waves (2Mx4N, wave tile 128x64).
// 4-way LDS ring (4 x 32KB), depth-2 prefetch via global_load_lds(16B),
// ONE raw s_barrier per K-step, counted s_waitcnt vmcnt(8) (never 0 in loop).
// Epilogue: relu(C + b1) . W2 row-reduce -> partial[m][nt].
// ---------------------------------------------------------------------------
__global__ __launch_bounds__(512, 2) void k1_gemm(
    const bf16_t* __restrict__ Abf,
    const bf16_t* __restrict__ Bbf,
    const float* __restrict__ b1,
    const float* __restrict__ W2,
    float* __restrict__ partial)    // [16384][NBLK]
{
  extern __shared__ __align__(16) unsigned char lds[];   // 131072 bytes

  const int tid  = threadIdx.x;           // 0..511
  // XCD-bijective swizzle (512 blocks % 8 == 0)
  const int wg   = (blockIdx.x & 7) * 64 + (blockIdx.x >> 3);
  const int mt   = wg >> 3;               // 0..63
  const int nt   = wg & 7;                // 0..7
  const int m0   = mt * 256;
  const int n0   = nt * 256;
  const int lane = tid & 63;
  const int wave = tid >> 6;              // 0..7
  const int wr = wave >> 2, wc = wave & 3;
  const int lr = lane & 15, lk = lane >> 4;

  const char* aT = (const char*)Abf + ((size_t)mt * 32) * TILE_BYTES;
  const char* bT = (const char*)Bbf + ((size_t)nt * 32) * TILE_BYTES;

  f32x4_t acc[8][4];
#pragma unroll
  for (int m = 0; m < 8; ++m)
#pragma unroll
    for (int n = 0; n < 4; ++n)
      acc[m][n] = (f32x4_t){0.f, 0.f, 0.f, 0.f};

  // stage K-step t into ring buffer buf: A tile 16KB then B tile 16KB
  auto stage = [&](int t, int buf) {
    const char* ga = aT + (size_t)t * TILE_BYTES;
    const char* gb = bT + (size_t)t * TILE_BYTES;
    unsigned char* lb = lds + buf * 32768;
#pragma unroll
    for (int j = 0; j < 4; ++j) {
      const int i = j * 512 + tid;        // 0..2047 16B-chunks
      const char* g = (j < 2) ? ga + i * 16 : gb + (i - 1024) * 16;
      __builtin_amdgcn_global_load_lds(
          (const __attribute__((address_space(1))) void*)g,
          (__attribute__((address_space(3))) void*)(lb + i * 16),
          16, 0, 0);
    }
  };

  stage(0, 0);
  stage(1, 1);
  for (int t = 0; t < NK; ++t) {
    if (t + 2 < NK) {
      stage(t + 2, (t + 2) & 3);
      asm volatile("s_waitcnt vmcnt(8)" ::: "memory");   // stage(t) landed
    } else if (t + 1 < NK) {
      asm volatile("s_waitcnt vmcnt(4)" ::: "memory");
    } else {
      asm volatile("s_waitcnt vmcnt(0)" ::: "memory");
    }
    __builtin_amdgcn_s_barrier();        // all waves' stage(t) shares visible
    asm volatile("" ::: "memory");       // no LDS reads hoist above barrier

    const char* sA = (const char*)(lds + (t & 3) * 32768);
    const char* sB = sA + 16384;
    bf16x8_t a[8], b[4];
#pragma unroll
    for (int m = 0; m < 8; ++m) {
      const int r = wr * 128 + m * 16 + lr;
      a[m] = *(const bf16x8_t*)(sA + r * 64 + ((lk ^ ((r >> 1) & 3)) << 4));
    }
#pragma unroll
    for (int n = 0; n < 4; ++n) {
      const int c = wc * 64 + n * 16 + lr;
      b[n] = *(const bf16x8_t*)(sB + c * 64 + ((lk ^ ((c >> 1) & 3)) << 4));
    }
    __builtin_amdgcn_s_setprio(1);
#pragma unroll
    for (int m = 0; m < 8; ++m)
#pragma unroll
      for (int n = 0; n < 4; ++n)
        acc[m][n] = __builtin_amdgcn_mfma_f32_16x16x32_bf16(a[m], b[n], acc[m][n], 0, 0, 0);
    __builtin_amdgcn_s_setprio(0);
  }

  // ---- epilogue: relu(C + b1) * W2, reduce over cols, write partial ----
  float rs[8][4];
#pragma unroll
  for (int m = 0; m < 8; ++m)
#pragma unroll
    for (int rg = 0; rg < 4; ++rg) rs[m][rg] = 0.f;

#pragma unroll
  for (int n = 0; n < 4; ++n) {
    const int jg = n0 + wc * 64 + n * 16 + lr;   // C/D: col = lane&15
    const float w2v = W2[jg];
    const float b1v = b1[jg];
#pragma unroll
    for (int m = 0; m < 8; ++m)
#pragma unroll
      for (int rg = 0; rg < 4; ++rg) {
        float v = acc[m][n][rg] + b1v;
        rs[m][rg] += fmaxf(v, 0.f) * w2v;
      }
  }
#pragma unroll
  for (int m = 0; m < 8; ++m)
#pragma unroll
    for (int rg = 0; rg < 4; ++rg) {
      float v = rs[m][rg];
      v += __shfl_xor(v, 1);
      v += __shfl_xor(v, 2);
      v += __shfl_xor(v, 4);
      v += __shfl_xor(v, 8);
      rs[m][rg] = v;                      // col-sum of this wave's 64-col slab
    }
  __syncthreads();                        // all frag reads done; alias lds
  float (*part_lds)[4] = (float(*)[4])lds;   // [256][4]
  if (lr == 0) {
#pragma unroll
    for (int m = 0; m < 8; ++m)
#pragma unroll
      for (int rg = 0; rg < 4; ++rg)
        part_lds[wr * 128 + m * 16 + lk * 4 + rg][wc] = rs[m][rg];
  }
  __syncthreads();
  if (tid < 256) {
    const float sum = part_lds[tid][0] + part_lds[tid][1]
                    + part_lds[tid][2] + part_lds[tid][3];
    partial[(size_t)(m0 + tid) * NBLK + nt] = sum;
  }
}

// ---------------------------------------------------------------------------
// K2a: logits[i] = b2 + sum(partial[i][:]); flag near-threshold tokens
// ---------------------------------------------------------------------------
__global__ __launch_bounds__(256) void k2a_logits(
    const float* __restrict__ partial,
    const float* __restrict__ b2,
    float* __restrict__ logits,
    int* __restrict__ flaglist,
    int* __restrict__ flagcnt)
{
  const int i = blockIdx.x * 256 + threadIdx.x;   // 0..16383
  const float* pp = partial + (size_t)i * NBLK;
  float lg = b2[0];
#pragma unroll
  for (int j = 0; j < NBLK; ++j) lg += pp[j];
  logits[i] = lg;
  if (fabsf(lg) < MARGIN) {
    int s = atomicAdd(flagcnt, 1);
    if (s < MAXFLAG) flaglist[s] = i;
  }
}

// ---------------------------------------------------------------------------
// K2b: exact f32 recompute of flagged rows (one block per flagged token)
// ---------------------------------------------------------------------------
__global__ __launch_bounds__(256) void k2b_fixup(
    const float* __restrict__ hidden,
    const float* __restrict__ W1,
    const float* __restrict__ b1,
    const float* __restrict__ W2,
    const float* __restrict__ b2,
    const int* __restrict__ flaglist,
    const int* __restrict__ flagcnt,
    float* __restrict__ logits)
{
  const int cnt = min(*flagcnt, MAXFLAG);
  if ((int)blockIdx.x >= cnt) return;
  __shared__ float hrow[D_];
  __shared__ float red[256];
  const int i = flaglist[blockIdx.x];
  const int tid = threadIdx.x;
  const float* h = hidden + (size_t)i * D_;
  *(f32x4_t*)&hrow[tid * 4] = *(const f32x4_t*)&h[tid * 4];
  __syncthreads();
  float acc8[8];
#pragma unroll
  for (int cc = 0; cc < 8; ++cc) acc8[cc] = 0.f;
  for (int k = 0; k < D_; ++k) {
    const float hv = hrow[k];
    const float* wrow = W1 + (size_t)k * H_;
#pragma unroll
    for (int cc = 0; cc < 8; ++cc)
      acc8[cc] = fmaf(hv, wrow[cc * 256 + tid], acc8[cc]);
  }
  float s = 0.f;
#pragma unroll
  for (int cc = 0; cc < 8; ++cc) {
    const int col = cc * 256 + tid;
    s += fmaxf(acc8[cc] + b1[col], 0.f) * W2[col];
  }
  red[tid] = s;
  __syncthreads();
  for (int st = 128; st > 0; st >>= 1) {
    if (tid < st) red[tid] += red[tid + st];
    __syncthreads();
  }
  if (tid == 0) logits[i] = red[0] + b2[0];
}

// ---------------------------------------------------------------------------
// K2c: per-batch scan (lengths, hb bits, segment starts, masks, NLL)
// ---------------------------------------------------------------------------
__global__ __launch_bounds__(256) void k2c_scan(
    const float* __restrict__ logits,    // [8][2048]
    const float* __restrict__ mask,      // [8][2048]
    const float* __restrict__ target,    // [8]
    float* __restrict__ outmask,         // [8][2048]
    int*   __restrict__ seg,             // [8][2050]
    float* __restrict__ hdr)             // [8][4]
{
  const int b = blockIdx.x, tid = threadIdx.x;
  __shared__ float redf[256];
  __shared__ int tsum[257];
  __shared__ unsigned char hbs[L_];

  float lm = 0.f;
#pragma unroll
  for (int e = 0; e < 8; ++e) lm += mask[b * L_ + tid * 8 + e];
  redf[tid] = lm;
  __syncthreads();
  for (int s = 128; s > 0; s >>= 1) {
    if (tid < s) redf[tid] += redf[tid + s];
    __syncthreads();
  }
  const int length = (int)(redf[0] + 0.5f);

  int hloc[8];
  int lsum = 0;
#pragma unroll
  for (int e = 0; e < 8; ++e) {
    const int t = tid * 8 + e;
    const float lg = logits[b * L_ + t];
    int hb = (lg > 0.f) && (t < length);
    if (length < L_ && t == length - 1) hb = 1;
    hloc[e] = hb;
    hbs[t] = (unsigned char)hb;
    lsum += hb;
  }
  tsum[tid] = lsum;
  __syncthreads();
  if (tid == 0) {
    int run = 0;
    for (int i = 0; i < 256; ++i) { int v = tsum[i]; tsum[i] = run; run += v; }
    tsum[256] = run;
  }
  __syncthreads();
  const int ktot = tsum[256];

  int pre = tsum[tid];
  for (int e = 0; e < 8; ++e) {
    const int t = tid * 8 + e;
    if (t < length) {
      const bool st = (t == 0) || hbs[t - 1];
      if (st) seg[b * 2050 + pre] = t;
    }
    pre += hloc[e];
  }

#pragma unroll
  for (int e = 0; e < 8; ++e) {
    const int t = tid * 8 + e;
    outmask[b * L_ + t] = (t < ktot) ? 1.f : 0.f;
  }

  __syncthreads();
  if (tid == 0) {
    const int maxseg = ktot - (length > 0 ? (int)hbs[length - 1] : 0);
    seg[b * 2050 + maxseg + 1] = length;
    const float n = (float)length, k = (float)ktot;
    float p = target[b] / fmaxf(n, 1.f);
    p = fminf(fmaxf(p, 1e-6f), 1.f - 1e-6f);
    const float lp = lgammaf(n + 1.f) - lgammaf(k + 1.f) - lgammaf(n - k + 1.f)
                   + k * logf(p) + (n - k) * log1pf(-p);
    hdr[b * 4 + 0] = n;
    hdr[b * 4 + 1] = k;
    hdr[b * 4 + 2] = (float)maxseg;
    hdr[b * 4 + 3] = -lp;
  }
}

// ---------------------------------------------------------------------------
// K3: the three scalars
// ---------------------------------------------------------------------------
__global__ void k3_final(const float* __restrict__ hdr, float* __restrict__ out3)
{
  if (threadIdx.x == 0 && blockIdx.x == 0) {
    float s_lp = 0.f, s_k = 0.f, s_n = 0.f;
    for (int b = 0; b < B_; ++b) {
      s_n  += hdr[b * 4 + 0];
      s_k  += hdr[b * 4 + 1];
      s_lp += hdr[b * 4 + 3];
    }
    out3[0] = 10.f * (s_lp * 0.125f);
    out3[1] = s_k;
    out3[2] = s_n;
  }
}

// ---------------------------------------------------------------------------
// K4b: pooled[b][s][:] = mean(hidden[b][st:en][:]) + PE[s][:]
// segment mean = edge rows + full 32-token chunk sums
// ---------------------------------------------------------------------------
__global__ __launch_bounds__(256) void k4b_pool(
    const float* __restrict__ hidden,
    const float* __restrict__ chunkSum,
    const int*   __restrict__ seg,
    const float* __restrict__ hdr,
    float* __restrict__ pooled)
{
  const int bid = blockIdx.x;
  const int b = bid >> 11, s = bid & 2047;
  const int tid = threadIdx.x;
  const int maxseg = (int)hdr[b * 4 + 2];

  float a0 = 0.f, a1 = 0.f, a2 = 0.f, a3 = 0.f;
  if (s <= maxseg) {
    const int st = seg[b * 2050 + s];
    const int en = seg[b * 2050 + s + 1];
    const float* hrow = hidden + (size_t)(b * L_) * D_ + tid * 4;
    const float* crow = chunkSum + (size_t)(b * NCH) * D_ + tid * 4;
    const int cs = (st + CHK - 1) / CHK;
    const int ce = en / CHK;
    if (cs >= ce) {
      for (int t = st; t < en; ++t) {
        const f32x4_t v = *(const f32x4_t*)(hrow + (size_t)t * D_);
        a0 += v.x; a1 += v.y; a2 += v.z; a3 += v.w;
      }
    } else {
      for (int t = st; t < cs * CHK; ++t) {
        const f32x4_t v = *(const f32x4_t*)(hrow + (size_t)t * D_);
        a0 += v.x; a1 += v.y; a2 += v.z; a3 += v.w;
      }
#pragma unroll 4
      for (int c = cs; c < ce; ++c) {
        const f32x4_t v = *(const f32x4_t*)(crow + (size_t)c * D_);
        a0 += v.x; a1 += v.y; a2 += v.z; a3 += v.w;
      }
      for (int t = ce * CHK; t < en; ++t) {
        const f32x4_t v = *(const f32x4_t*)(hrow + (size_t)t * D_);
        a0 += v.x; a1 += v.y; a2 += v.z; a3 += v.w;
      }
    }
    const float cnt = (float)(en - st);
    const float inv = 1.f / (cnt + 1e-9f);
    a0 *= inv; a1 *= inv; a2 *= inv; a3 *= inv;
  }
  const float e0 = (float)(4 * tid)     * (1.f / 1024.f);
  const float e1 = (float)(4 * tid + 2) * (1.f / 1024.f);
  const float ang0 = (float)s / powf(10000.f, e0);
  const float ang1 = (float)s / powf(10000.f, e1);
  float s0, c0, s1, c1;
  sincosf(ang0, &s0, &c0);
  sincosf(ang1, &s1, &c1);
  f32x4_t o;
  o.x = a0 + s0; o.y = a1 + c0; o.z = a2 + s1; o.w = a3 + c1;
  *(f32x4_t*)(pooled + ((size_t)(b * L_ + s)) * D_ + tid * 4) = o;
}

// ---------------------------------------------------------------------------
extern "C" void kernel_launch(void* const* d_in, const int* in_sizes, int n_in,
                              void* d_out, int out_size, void* d_ws, size_t ws_size,
                              hipStream_t stream)
{
  (void)in_sizes; (void)n_in; (void)out_size; (void)ws_size;
  const float* hidden = (const float*)d_in[0];
  const float* amask  = (const float*)d_in[1];
  const float* target = (const float*)d_in[2];
  const float* W1     = (const float*)d_in[3];
  const float* b1     = (const float*)d_in[4];
  const float* W2     = (const float*)d_in[5];
  const float* b2     = (const float*)d_in[6];

  float* out     = (float*)d_out;
  float* pooled  = out;                       // 16777216 floats (written LAST)
  float* out3    = out + 16777216;
  float* outmask = out + 16777219;

  // Abf (32MB) + Bbf (4MB) live inside the pooled output region as scratch;
  // k4b fully overwrites pooled afterwards.
  bf16_t* Abf = (bf16_t*)out;                       // 32 MB
  bf16_t* Bbf = (bf16_t*)(out + 8388608);           // 4 MB at byte offset 32MB

  char* ws = (char*)d_ws;
  float* partial  = (float*)ws;                      ws += (size_t)16384 * NBLK * 4;  // 512 KB
  int*   seg      = (int*)ws;                        ws += (size_t)B_ * 2050 * 4;
  float* hdr      = (float*)ws;                      ws += (size_t)B_ * 4 * 4;
  float* logits   = (float*)ws;                      ws += (size_t)B_ * L_ * 4;       // 64 KB
  int*   flaglist = (int*)ws;                        ws += (size_t)MAXFLAG * 4;
  int*   flagcnt  = (int*)ws;                        ws += 256;
  float* chunkSum = (float*)ws;                      // 2 MB

  hipMemsetAsync(flagcnt, 0, 4, stream);
  k0a_packA<<<dim3(32, 64), dim3(256), 0, stream>>>(hidden, Abf, chunkSum);
  k0b_packB<<<dim3(32, 8), dim3(256), 0, stream>>>(W1, Bbf);
  k1_gemm<<<dim3(512), dim3(512), 131072, stream>>>(Abf, Bbf, b1, W2, partial);
  k2a_logits<<<dim3(64), dim3(256), 0, stream>>>(partial, b2, logits, flaglist, flagcnt);
  k2b_fixup<<<dim3(MAXFLAG), dim3(256), 0, stream>>>(hidden, W1, b1, W2, b2,
                                                     flaglist, flagcnt, logits);
  k2c_scan<<<dim3(8), dim3(256), 0, stream>>>(logits, amask, target, outmask, seg, hdr);
  k3_final<<<dim3(1), dim3(64), 0, stream>>>(hdr, out3);
  k4b_pool<<<dim3(16384), dim3(256), 0, stream>>>(hidden, chunkSum, seg, hdr, pooled);
}

// Round 5
// 141.621 us; speedup vs baseline: 5.2589x; 1.0477x over previous
//
#include <hip/hip_runtime.h>
#include <math.h>

#define B_   8
#define L_   2048
#define D_   1024
#define H_   2048
#define NBLK 8             // H_/256 N-tiles in the GEMM
#define CHK  32            // tokens per chunk in pooling pre-pass
#define NCH  (L_ / CHK)    // 64 chunks per batch item
#define BK   64
#define NK   (D_ / BK)     // 16 K-tiles
#define MARGIN  0.05f      // |logit| below this -> exact f32 recompute
#define MAXFLAG 1024

typedef __bf16 bf16_t;
typedef bf16_t bf16x8_t __attribute__((ext_vector_type(8)));
typedef float  f32x4_t  __attribute__((ext_vector_type(4)));

// Packed tile images, fragment-linear so k1's ds_read_b128 is base+lane*16:
// A tile (mt,kt) = 32KB: [kh 2][rowblock 16][lane 64][16B]
//   lane = kgrp*16 + (row&15), rowblock = row>>4, k = kh*32 + kgrp*8 + e
// B tile (nt,kt) = 32KB: same with columns.
#define TILE_BYTES 32768

// ---------------------------------------------------------------------------
// K0a (fused): hidden f32 -> Abf packed tiles  AND  32-token chunk sums
// grid (kt=16, mt=64), 256 threads; thread r owns row r of the tile.
// ---------------------------------------------------------------------------
__global__ __launch_bounds__(256) void k0a_packA(
    const float* __restrict__ A,      // [16384][1024]
    bf16_t* __restrict__ Abf,         // [64 mt][16 kt] tiles of 32KB
    float* __restrict__ chunkSum)     // [8][NCH][1024]
{
  __shared__ float scratch[256][65];
  const int kt = blockIdx.x;   // 0..15
  const int mt = blockIdx.y;   // 0..63
  const int r  = threadIdx.x;  // 0..255
  const float* src = A + (size_t)(mt * 256 + r) * D_ + kt * BK;
  float v[64];
#pragma unroll
  for (int q = 0; q < 16; ++q) {
    f32x4_t x = *(const f32x4_t*)(src + q * 4);
    v[q*4] = x.x; v[q*4+1] = x.y; v[q*4+2] = x.z; v[q*4+3] = x.w;
  }
  char* dst = (char*)Abf + ((size_t)(mt * 16 + kt)) * TILE_BYTES
            + (r >> 4) * 1024 + (r & 15) * 16;
#pragma unroll
  for (int kh = 0; kh < 2; ++kh)
#pragma unroll
    for (int kg = 0; kg < 4; ++kg) {
      bf16x8_t o;
#pragma unroll
      for (int e = 0; e < 8; ++e) o[e] = (bf16_t)v[kh * 32 + kg * 8 + e];
      *(bf16x8_t*)(dst + kh * 16384 + kg * 256) = o;
    }
  // chunk sums: tile spans 256 tokens = 8 chunks of 32
#pragma unroll
  for (int q = 0; q < 16; ++q)
    *(f32x4_t*)&scratch[r][q * 4] = *(const f32x4_t*)&v[q * 4];
  __syncthreads();
  const int ch = r >> 5, j2 = r & 31;
#pragma unroll
  for (int half = 0; half < 2; ++half) {
    const int j = j2 + half * 32;
    float s = 0.f;
#pragma unroll
    for (int q = 0; q < 32; ++q) s += scratch[ch * 32 + q][j];
    const int b  = mt >> 3;
    const int cg = (mt & 7) * 8 + ch;
    chunkSum[((size_t)(b * NCH + cg)) * D_ + kt * BK + j] = s;
  }
}

// ---------------------------------------------------------------------------
// K0b: W1 f32 -> Bbf packed tiles; also zeroes flagcnt
// ---------------------------------------------------------------------------
__global__ __launch_bounds__(256) void k0b_packB(
    const float* __restrict__ W1,     // [1024][2048]
    bf16_t* __restrict__ Bbf,         // [8 nt][16 kt] tiles of 32KB
    int* __restrict__ flagcnt)
{
  const int kt = blockIdx.x;   // 0..15
  const int nt = blockIdx.y;   // 0..7
  const int c  = threadIdx.x;  // 0..255
  if (kt == 0 && nt == 0 && c == 0) *flagcnt = 0;
  const float* src = W1 + (size_t)(kt * BK) * H_ + nt * 256 + c;
  float v[64];
#pragma unroll
  for (int j = 0; j < 64; ++j) v[j] = src[(size_t)j * H_];
  char* dst = (char*)Bbf + ((size_t)(nt * 16 + kt)) * TILE_BYTES
            + (c >> 4) * 1024 + (c & 15) * 16;
#pragma unroll
  for (int kh = 0; kh < 2; ++kh)
#pragma unroll
    for (int kg = 0; kg < 4; ++kg) {
      bf16x8_t o;
#pragma unroll
      for (int e = 0; e < 8; ++e) o[e] = (bf16_t)v[kh * 32 + kg * 8 + e];
      *(bf16x8_t*)(dst + kh * 16384 + kg * 256) = o;
    }
}

// ---------------------------------------------------------------------------
// K1: bf16 GEMM 256x256 tile, BK=64, 8 waves (2Mx4N, wave tile 128x64).
// 4 phases per K-tile: {kh0 m0-3 (+B kh0), kh0 m4-7, kh1 m0-3 (+B kh1),
// kh1 m4-7}; one 16KB half-tile staged per phase via 2 gload_lds/thread;
// 2 barriers/phase; counted vmcnt(8) at phases 1,3 (never 0 until t=14).
// Epilogue: relu(C + b1) . W2 row-reduce -> partial[m][nt].
// ---------------------------------------------------------------------------
__global__ __launch_bounds__(512, 2) void k1_gemm(
    const bf16_t* __restrict__ Abf,
    const bf16_t* __restrict__ Bbf,
    const float* __restrict__ b1,
    const float* __restrict__ W2,
    float* __restrict__ partial)    // [16384][NBLK]
{
  extern __shared__ __align__(16) unsigned char lds[];   // 131072 bytes

  const int tid  = threadIdx.x;           // 0..511
  const int wg   = (blockIdx.x & 7) * 64 + (blockIdx.x >> 3);  // XCD swizzle
  const int mt   = wg >> 3;               // 0..63
  const int nt   = wg & 7;                // 0..7
  const int m0   = mt * 256;
  const int n0   = nt * 256;
  const int lane = tid & 63;
  const int wave = tid >> 6;              // 0..7
  const int wr = wave >> 2, wc = wave & 3;
  const int lr = lane & 15, lk = lane >> 4;

  const char* aT = (const char*)Abf + (size_t)mt * 16 * TILE_BYTES;
  const char* bT = (const char*)Bbf + (size_t)nt * 16 * TILE_BYTES;

  f32x4_t acc[8][4];
#pragma unroll
  for (int m = 0; m < 8; ++m)
#pragma unroll
    for (int n = 0; n < 4; ++n)
      acc[m][n] = (f32x4_t){0.f, 0.f, 0.f, 0.f};

  // half-tile id: kt = id>>2, part = id&3 (0:A kh0, 1:B kh0, 2:A kh1, 3:B kh1)
  auto stage = [&](int id) {
    const int kt = id >> 2, part = id & 3;
    const char* g = ((part & 1) ? bT : aT)
                  + (size_t)kt * TILE_BYTES + (part >> 1) * 16384 + tid * 16;
    unsigned char* d = lds + (kt & 1) * 65536 + (part & 1) * 32768
                     + (part >> 1) * 16384 + tid * 16;
    __builtin_amdgcn_global_load_lds(
        (const __attribute__((address_space(1))) void*)g,
        (__attribute__((address_space(3))) void*)d, 16, 0, 0);
    __builtin_amdgcn_global_load_lds(
        (const __attribute__((address_space(1))) void*)(g + 8192),
        (__attribute__((address_space(3))) void*)(d + 8192), 16, 0, 0);
  };

  // prologue: K-tile 0 complete + A/B kh0 of K-tile 1
  for (int id = 0; id < 6; ++id) stage(id);
  asm volatile("s_waitcnt vmcnt(8)" ::: "memory");   // ids 0,1 landed
  __builtin_amdgcn_s_barrier();

  for (int t = 0; t < NK; ++t) {
    const unsigned char* bufA = lds + (t & 1) * 65536;
    const unsigned char* bufB = bufA + 32768;
    bf16x8_t bfr[4];
#pragma unroll
    for (int p = 0; p < 4; ++p) {
      const int kh = p >> 1, mh = p & 1;
      asm volatile("" ::: "memory");     // reads stay after previous barrier
      bf16x8_t afr[4];
#pragma unroll
      for (int i = 0; i < 4; ++i)
        afr[i] = *(const bf16x8_t*)(bufA + kh * 16384
                                    + (wr * 8 + mh * 4 + i) * 1024 + lane * 16);
      if (mh == 0) {
#pragma unroll
        for (int n = 0; n < 4; ++n)
          bfr[n] = *(const bf16x8_t*)(bufB + kh * 16384
                                      + (wc * 4 + n) * 1024 + lane * 16);
      }
      const int sid = 4 * t + 6 + p;
      if (sid < 4 * NK) stage(sid);
      if (p == 1) {
        asm volatile("s_waitcnt vmcnt(8)" ::: "memory");   // ids 4t+2,4t+3 landed
      } else if (p == 3) {
        if (t < NK - 2) asm volatile("s_waitcnt vmcnt(8)" ::: "memory");
        else if (t == NK - 2) asm volatile("s_waitcnt vmcnt(0)" ::: "memory");
      }
      __builtin_amdgcn_s_barrier();
      asm volatile("" ::: "memory");
      __builtin_amdgcn_s_setprio(1);
#pragma unroll
      for (int i = 0; i < 4; ++i)
#pragma unroll
        for (int n = 0; n < 4; ++n)
          acc[mh * 4 + i][n] = __builtin_amdgcn_mfma_f32_16x16x32_bf16(
              afr[i], bfr[n], acc[mh * 4 + i][n], 0, 0, 0);
      __builtin_amdgcn_s_setprio(0);
      __builtin_amdgcn_s_barrier();
    }
  }

  // ---- epilogue: relu(C + b1) * W2, reduce over cols, write partial ----
  float rs[8][4];
#pragma unroll
  for (int m = 0; m < 8; ++m)
#pragma unroll
    for (int rg = 0; rg < 4; ++rg) rs[m][rg] = 0.f;

#pragma unroll
  for (int n = 0; n < 4; ++n) {
    const int jg = n0 + wc * 64 + n * 16 + lr;   // C/D: col = lane&15
    const float w2v = W2[jg];
    const float b1v = b1[jg];
#pragma unroll
    for (int m = 0; m < 8; ++m)
#pragma unroll
      for (int rg = 0; rg < 4; ++rg) {
        float v = acc[m][n][rg] + b1v;
        rs[m][rg] += fmaxf(v, 0.f) * w2v;
      }
  }
#pragma unroll
  for (int m = 0; m < 8; ++m)
#pragma unroll
    for (int rg = 0; rg < 4; ++rg) {
      float v = rs[m][rg];
      v += __shfl_xor(v, 1);
      v += __shfl_xor(v, 2);
      v += __shfl_xor(v, 4);
      v += __shfl_xor(v, 8);
      rs[m][rg] = v;                      // col-sum of this wave's 64-col slab
    }
  __syncthreads();                        // all frag reads done; alias lds
  float (*part_lds)[4] = (float(*)[4])lds;   // [256][4]
  if (lr == 0) {
#pragma unroll
    for (int m = 0; m < 8; ++m)
#pragma unroll
      for (int rg = 0; rg < 4; ++rg)
        part_lds[wr * 128 + m * 16 + lk * 4 + rg][wc] = rs[m][rg];
  }
  __syncthreads();
  if (tid < 256) {
    const float sum = part_lds[tid][0] + part_lds[tid][1]
                    + part_lds[tid][2] + part_lds[tid][3];
    partial[(size_t)(m0 + tid) * NBLK + nt] = sum;
  }
}

// ---------------------------------------------------------------------------
// K2a: logits[i] = b2 + sum(partial[i][:]); flag near-threshold tokens
// ---------------------------------------------------------------------------
__global__ __launch_bounds__(256) void k2a_logits(
    const float* __restrict__ partial,
    const float* __restrict__ b2,
    float* __restrict__ logits,
    int* __restrict__ flaglist,
    int* __restrict__ flagcnt)
{
  const int i = blockIdx.x * 256 + threadIdx.x;   // 0..16383
  const float* pp = partial + (size_t)i * NBLK;
  float lg = b2[0];
#pragma unroll
  for (int j = 0; j < NBLK; ++j) lg += pp[j];
  logits[i] = lg;
  if (fabsf(lg) < MARGIN) {
    int s = atomicAdd(flagcnt, 1);
    if (s < MAXFLAG) flaglist[s] = i;
  }
}

// ---------------------------------------------------------------------------
// K2b: exact f32 recompute of flagged rows (256 blocks, stride over flags)
// ---------------------------------------------------------------------------
__global__ __launch_bounds__(256) void k2b_fixup(
    const float* __restrict__ hidden,
    const float* __restrict__ W1,
    const float* __restrict__ b1,
    const float* __restrict__ W2,
    const float* __restrict__ b2,
    const int* __restrict__ flaglist,
    const int* __restrict__ flagcnt,
    float* __restrict__ logits)
{
  const int cnt = min(*flagcnt, MAXFLAG);
  __shared__ float hrow[D_];
  __shared__ float red[256];
  const int tid = threadIdx.x;
  for (int f = blockIdx.x; f < cnt; f += 256) {
    const int i = flaglist[f];
    const float* h = hidden + (size_t)i * D_;
    __syncthreads();
    *(f32x4_t*)&hrow[tid * 4] = *(const f32x4_t*)&h[tid * 4];
    __syncthreads();
    float acc8[8];
#pragma unroll
    for (int cc = 0; cc < 8; ++cc) acc8[cc] = 0.f;
    for (int k = 0; k < D_; ++k) {
      const float hv = hrow[k];
      const float* wrow = W1 + (size_t)k * H_;
#pragma unroll
      for (int cc = 0; cc < 8; ++cc)
        acc8[cc] = fmaf(hv, wrow[cc * 256 + tid], acc8[cc]);
    }
    float s = 0.f;
#pragma unroll
    for (int cc = 0; cc < 8; ++cc) {
      const int col = cc * 256 + tid;
      s += fmaxf(acc8[cc] + b1[col], 0.f) * W2[col];
    }
    red[tid] = s;
    __syncthreads();
    for (int st = 128; st > 0; st >>= 1) {
      if (tid < st) red[tid] += red[tid + st];
      __syncthreads();
    }
    if (tid == 0) logits[i] = red[0] + b2[0];
  }
}

// ---------------------------------------------------------------------------
// K2c: per-batch scan (lengths, hb bits, segment starts, masks, NLL)
// ---------------------------------------------------------------------------
__global__ __launch_bounds__(256) void k2c_scan(
    const float* __restrict__ logits,    // [8][2048]
    const float* __restrict__ mask,      // [8][2048]
    const float* __restrict__ target,    // [8]
    float* __restrict__ outmask,         // [8][2048]
    int*   __restrict__ seg,             // [8][2050]
    float* __restrict__ hdr)             // [8][4]
{
  const int b = blockIdx.x, tid = threadIdx.x;
  __shared__ float redf[256];
  __shared__ int tsum[257];
  __shared__ unsigned char hbs[L_];

  float lm = 0.f;
#pragma unroll
  for (int e = 0; e < 8; ++e) lm += mask[b * L_ + tid * 8 + e];
  redf[tid] = lm;
  __syncthreads();
  for (int s = 128; s > 0; s >>= 1) {
    if (tid < s) redf[tid] += redf[tid + s];
    __syncthreads();
  }
  const int length = (int)(redf[0] + 0.5f);

  int hloc[8];
  int lsum = 0;
#pragma unroll
  for (int e = 0; e < 8; ++e) {
    const int t = tid * 8 + e;
    const float lg = logits[b * L_ + t];
    int hb = (lg > 0.f) && (t < length);
    if (length < L_ && t == length - 1) hb = 1;
    hloc[e] = hb;
    hbs[t] = (unsigned char)hb;
    lsum += hb;
  }
  tsum[tid] = lsum;
  __syncthreads();
  if (tid == 0) {
    int run = 0;
    for (int i = 0; i < 256; ++i) { int v = tsum[i]; tsum[i] = run; run += v; }
    tsum[256] = run;
  }
  __syncthreads();
  const int ktot = tsum[256];

  int pre = tsum[tid];
  for (int e = 0; e < 8; ++e) {
    const int t = tid * 8 + e;
    if (t < length) {
      const bool st = (t == 0) || hbs[t - 1];
      if (st) seg[b * 2050 + pre] = t;
    }
    pre += hloc[e];
  }

#pragma unroll
  for (int e = 0; e < 8; ++e) {
    const int t = tid * 8 + e;
    outmask[b * L_ + t] = (t < ktot) ? 1.f : 0.f;
  }

  __syncthreads();
  if (tid == 0) {
    const int maxseg = ktot - (length > 0 ? (int)hbs[length - 1] : 0);
    seg[b * 2050 + maxseg + 1] = length;
    const float n = (float)length, k = (float)ktot;
    float p = target[b] / fmaxf(n, 1.f);
    p = fminf(fmaxf(p, 1e-6f), 1.f - 1e-6f);
    const float lp = lgammaf(n + 1.f) - lgammaf(k + 1.f) - lgammaf(n - k + 1.f)
                   + k * logf(p) + (n - k) * log1pf(-p);
    hdr[b * 4 + 0] = n;
    hdr[b * 4 + 1] = k;
    hdr[b * 4 + 2] = (float)maxseg;
    hdr[b * 4 + 3] = -lp;
  }
}

// ---------------------------------------------------------------------------
// K4b: pooled[b][s][:] = mean(hidden[b][st:en][:]) + PE[s][:]
// segment mean = edge rows + full 32-token chunk sums. Block 0 also emits
// the three scalars (loss, num_boundaries, total_positions).
// ---------------------------------------------------------------------------
__global__ __launch_bounds__(256) void k4b_pool(
    const float* __restrict__ hidden,
    const float* __restrict__ chunkSum,
    const int*   __restrict__ seg,
    const float* __restrict__ hdr,
    float* __restrict__ pooled,
    float* __restrict__ out3)
{
  const int bid = blockIdx.x;
  const int b = bid >> 11, s = bid & 2047;
  const int tid = threadIdx.x;
  if (bid == 0 && tid == 0) {
    float s_lp = 0.f, s_k = 0.f, s_n = 0.f;
    for (int i = 0; i < B_; ++i) {
      s_n  += hdr[i * 4 + 0];
      s_k  += hdr[i * 4 + 1];
      s_lp += hdr[i * 4 + 3];
    }
    out3[0] = 10.f * (s_lp * 0.125f);
    out3[1] = s_k;
    out3[2] = s_n;
  }
  const int maxseg = (int)hdr[b * 4 + 2];

  float a0 = 0.f, a1 = 0.f, a2 = 0.f, a3 = 0.f;
  if (s <= maxseg) {
    const int st = seg[b * 2050 + s];
    const int en = seg[b * 2050 + s + 1];
    const float* hrow = hidden + (size_t)(b * L_) * D_ + tid * 4;
    const float* crow = chunkSum + (size_t)(b * NCH) * D_ + tid * 4;
    const int cs = (st + CHK - 1) / CHK;
    const int ce = en / CHK;
    if (cs >= ce) {
      for (int t = st; t < en; ++t) {
        const f32x4_t v = *(const f32x4_t*)(hrow + (size_t)t * D_);
        a0 += v.x; a1 += v.y; a2 += v.z; a3 += v.w;
      }
    } else {
      for (int t = st; t < cs * CHK; ++t) {
        const f32x4_t v = *(const f32x4_t*)(hrow + (size_t)t * D_);
        a0 += v.x; a1 += v.y; a2 += v.z; a3 += v.w;
      }
#pragma unroll 4
      for (int c = cs; c < ce; ++c) {
        const f32x4_t v = *(const f32x4_t*)(crow + (size_t)c * D_);
        a0 += v.x; a1 += v.y; a2 += v.z; a3 += v.w;
      }
      for (int t = ce * CHK; t < en; ++t) {
        const f32x4_t v = *(const f32x4_t*)(hrow + (size_t)t * D_);
        a0 += v.x; a1 += v.y; a2 += v.z; a3 += v.w;
      }
    }
    const float cnt = (float)(en - st);
    const float inv = 1.f / (cnt + 1e-9f);
    a0 *= inv; a1 *= inv; a2 *= inv; a3 *= inv;
  }
  const float e0 = (float)(4 * tid)     * (1.f / 1024.f);
  const float e1 = (float)(4 * tid + 2) * (1.f / 1024.f);
  const float ang0 = (float)s / powf(10000.f, e0);
  const float ang1 = (float)s / powf(10000.f, e1);
  float s0, c0, s1, c1;
  sincosf(ang0, &s0, &c0);
  sincosf(ang1, &s1, &c1);
  f32x4_t o;
  o.x = a0 + s0; o.y = a1 + c0; o.z = a2 + s1; o.w = a3 + c1;
  *(f32x4_t*)(pooled + ((size_t)(b * L_ + s)) * D_ + tid * 4) = o;
}

// ---------------------------------------------------------------------------
extern "C" void kernel_launch(void* const* d_in, const int* in_sizes, int n_in,
                              void* d_out, int out_size, void* d_ws, size_t ws_size,
                              hipStream_t stream)
{
  (void)in_sizes; (void)n_in; (void)out_size; (void)ws_size;
  const float* hidden = (const float*)d_in[0];
  const float* amask  = (const float*)d_in[1];
  const float* target = (const float*)d_in[2];
  const float* W1     = (const float*)d_in[3];
  const float* b1     = (const float*)d_in[4];
  const float* W2     = (const float*)d_in[5];
  const float* b2     = (const float*)d_in[6];

  float* out     = (float*)d_out;
  float* pooled  = out;                       // 16777216 floats (written LAST)
  float* out3    = out + 16777216;
  float* outmask = out + 16777219;

  // Abf (32MB) + Bbf (4MB) live inside the pooled output region as scratch;
  // k4b fully overwrites pooled afterwards.
  bf16_t* Abf = (bf16_t*)out;                       // 32 MB
  bf16_t* Bbf = (bf16_t*)(out + 8388608);           // 4 MB at byte offset 32MB

  char* ws = (char*)d_ws;
  float* partial  = (float*)ws;                      ws += (size_t)16384 * NBLK * 4;  // 512 KB
  int*   seg      = (int*)ws;                        ws += (size_t)B_ * 2050 * 4;
  float* hdr      = (float*)ws;                      ws += (size_t)B_ * 4 * 4;
  float* logits   = (float*)ws;                      ws += (size_t)B_ * L_ * 4;       // 64 KB
  int*   flaglist = (int*)ws;                        ws += (size_t)MAXFLAG * 4;
  int*   flagcnt  = (int*)ws;                        ws += 256;
  float* chunkSum = (float*)ws;                      // 2 MB

  k0a_packA<<<dim3(16, 64), dim3(256), 0, stream>>>(hidden, Abf, chunkSum);
  k0b_packB<<<dim3(16, 8), dim3(256), 0, stream>>>(W1, Bbf, flagcnt);
  k1_gemm<<<dim3(512), dim3(512), 131072, stream>>>(Abf, Bbf, b1, W2, partial);
  k2a_logits<<<dim3(64), dim3(256), 0, stream>>>(partial, b2, logits, flaglist, flagcnt);
  k2b_fixup<<<dim3(256), dim3(256), 0, stream>>>(hidden, W1, b1, W2, b2,
                                                 flaglist, flagcnt, logits);
  k2c_scan<<<dim3(8), dim3(256), 0, stream>>>(logits, amask, target, outmask, seg, hdr);
  k4b_pool<<<dim3(16384), dim3(256), 0, stream>>>(hidden, chunkSum, seg, hdr, pooled, out3);
}

// Round 6
// 140.249 us; speedup vs baseline: 5.3104x; 1.0098x over previous
//
#include <hip/hip_runtime.h>
#include <math.h>

#define B_   8
#define L_   2048
#define D_   1024
#define H_   2048
#define NBLK 8             // H_/256 N-tiles in the GEMM
#define CHK  32            // tokens per chunk in pooling pre-pass
#define NCH  (L_ / CHK)    // 64 chunks per batch item
#define BK   32
#define NK   (D_ / BK)     // 32 K-steps
#define MARGIN  0.05f      // |logit| below this -> exact f32 recompute
#define MAXFLAG 1024

typedef __bf16 bf16_t;
typedef bf16_t bf16x8_t __attribute__((ext_vector_type(8)));
typedef float  f32x4_t  __attribute__((ext_vector_type(4)));
typedef float  f32x16_t __attribute__((ext_vector_type(16)));

// Packed tile images, fragment-linear for 32x32x16 MFMA so k1's ds_read_b128
// is base + lane*16 (conflict-free linear wave read):
// A tile (mt,kt) = 256 rows x 32 k bf16 = 16KB.
//   byte(row,k) = (row>>5)*2048 + (k>>4)*1024 + ((k>>3)&1)*512
//               + (row&31)*16 + (k&7)*2
// B tile (nt,kt): same with columns.
#define TILE_BYTES 16384

// ---------------------------------------------------------------------------
// K0a (fused): hidden f32 -> Abf packed tiles AND 32-token chunk sums
// grid (kt=32, mt=64), 256 threads; thread r owns row r of the tile.
// ---------------------------------------------------------------------------
__global__ __launch_bounds__(256) void k0a_packA(
    const float* __restrict__ A,      // [16384][1024]
    bf16_t* __restrict__ Abf,         // [64 mt][32 kt] tiles of 16KB
    float* __restrict__ chunkSum)     // [8][NCH][1024]
{
  __shared__ float scratch[256][33];
  const int kt = blockIdx.x;   // 0..31
  const int mt = blockIdx.y;   // 0..63
  const int r  = threadIdx.x;  // 0..255
  const float* src = A + (size_t)(mt * 256 + r) * D_ + kt * BK;
  float v[32];
#pragma unroll
  for (int q = 0; q < 8; ++q) {
    f32x4_t x = *(const f32x4_t*)(src + q * 4);
    v[q*4] = x.x; v[q*4+1] = x.y; v[q*4+2] = x.z; v[q*4+3] = x.w;
  }
  char* dst = (char*)Abf + ((size_t)(mt * 32 + kt)) * TILE_BYTES
            + (r >> 5) * 2048 + (r & 31) * 16;
#pragma unroll
  for (int ks = 0; ks < 2; ++ks)
#pragma unroll
    for (int kg = 0; kg < 2; ++kg) {
      bf16x8_t o;
#pragma unroll
      for (int e = 0; e < 8; ++e) o[e] = (bf16_t)v[ks * 16 + kg * 8 + e];
      *(bf16x8_t*)(dst + ks * 1024 + kg * 512) = o;
    }
  // chunk sums: tile spans 256 tokens = 8 chunks of 32
#pragma unroll
  for (int q = 0; q < 8; ++q)
    *(f32x4_t*)&scratch[r][q * 4] = *(const f32x4_t*)&v[q * 4];
  __syncthreads();
  const int ch = r >> 5, j = r & 31;
  float s = 0.f;
#pragma unroll
  for (int q = 0; q < 32; ++q) s += scratch[ch * 32 + q][j];
  const int b  = mt >> 3;
  const int cg = (mt & 7) * 8 + ch;
  chunkSum[((size_t)(b * NCH + cg)) * D_ + kt * BK + j] = s;
}

// ---------------------------------------------------------------------------
// K0b: W1 f32 -> Bbf packed tiles; also zeroes flagcnt
// ---------------------------------------------------------------------------
__global__ __launch_bounds__(256) void k0b_packB(
    const float* __restrict__ W1,     // [1024][2048]
    bf16_t* __restrict__ Bbf,         // [8 nt][32 kt] tiles of 16KB
    int* __restrict__ flagcnt)
{
  const int kt = blockIdx.x;   // 0..31
  const int nt = blockIdx.y;   // 0..7
  const int c  = threadIdx.x;  // 0..255
  if (kt == 0 && nt == 0 && c == 0) *flagcnt = 0;
  const float* src = W1 + (size_t)(kt * BK) * H_ + nt * 256 + c;
  float v[32];
#pragma unroll
  for (int j = 0; j < 32; ++j) v[j] = src[(size_t)j * H_];
  char* dst = (char*)Bbf + ((size_t)(nt * 32 + kt)) * TILE_BYTES
            + (c >> 5) * 2048 + (c & 31) * 16;
#pragma unroll
  for (int ks = 0; ks < 2; ++ks)
#pragma unroll
    for (int kg = 0; kg < 2; ++kg) {
      bf16x8_t o;
#pragma unroll
      for (int e = 0; e < 8; ++e) o[e] = (bf16_t)v[ks * 16 + kg * 8 + e];
      *(bf16x8_t*)(dst + ks * 1024 + kg * 512) = o;
    }
}

// ---------------------------------------------------------------------------
// K1: bf16 GEMM 256x256 tile, BK=32, 8 waves (2Mx4N, wave tile 128x64),
// v_mfma_f32_32x32x16_bf16 (half the MFMA issues of 16x16x32).
// 4-way LDS ring (4 x 32KB), depth-2 prefetch via global_load_lds(16B),
// ONE raw s_barrier per K-step, counted s_waitcnt vmcnt(8) (never 0 in loop).
// Epilogue: relu(C + b1) . W2 row-reduce -> partial[m][nt].
// ---------------------------------------------------------------------------
__global__ __launch_bounds__(512, 2) void k1_gemm(
    const bf16_t* __restrict__ Abf,
    const bf16_t* __restrict__ Bbf,
    const float* __restrict__ b1,
    const float* __restrict__ W2,
    float* __restrict__ partial)    // [16384][NBLK]
{
  extern __shared__ __align__(16) unsigned char lds[];   // 131072 bytes

  const int tid  = threadIdx.x;           // 0..511
  const int wg   = (blockIdx.x & 7) * 64 + (blockIdx.x >> 3);  // XCD swizzle
  const int mt   = wg >> 3;               // 0..63
  const int nt   = wg & 7;                // 0..7
  const int m0   = mt * 256;
  const int n0   = nt * 256;
  const int lane = tid & 63;
  const int wave = tid >> 6;              // 0..7
  const int wr = wave >> 2, wc = wave & 3;
  const int l5 = lane & 31, hi = lane >> 5;

  const char* aT = (const char*)Abf + (size_t)mt * 32 * TILE_BYTES;
  const char* bT = (const char*)Bbf + (size_t)nt * 32 * TILE_BYTES;

  f32x16_t acc[4][2];
#pragma unroll
  for (int m = 0; m < 4; ++m)
#pragma unroll
    for (int n = 0; n < 2; ++n)
#pragma unroll
      for (int i = 0; i < 16; ++i) acc[m][n][i] = 0.f;

  // stage K-step t into ring buffer buf: A tile 16KB then B tile 16KB
  auto stage = [&](int t, int buf) {
    const char* ga = aT + (size_t)t * TILE_BYTES;
    const char* gb = bT + (size_t)t * TILE_BYTES;
    unsigned char* lb = lds + buf * 32768;
#pragma unroll
    for (int j = 0; j < 4; ++j) {
      const int i = j * 512 + tid;        // 0..2047 16B-chunks
      const char* g = (j < 2) ? ga + i * 16 : gb + (i - 1024) * 16;
      __builtin_amdgcn_global_load_lds(
          (const __attribute__((address_space(1))) void*)g,
          (__attribute__((address_space(3))) void*)(lb + i * 16),
          16, 0, 0);
    }
  };

  stage(0, 0);
  stage(1, 1);
  for (int t = 0; t < NK; ++t) {
    if (t + 2 < NK) {
      stage(t + 2, (t + 2) & 3);
      asm volatile("s_waitcnt vmcnt(8)" ::: "memory");   // stage(t) landed
    } else if (t + 1 < NK) {
      asm volatile("s_waitcnt vmcnt(4)" ::: "memory");
    } else {
      asm volatile("s_waitcnt vmcnt(0)" ::: "memory");
    }
    __builtin_amdgcn_s_barrier();        // all waves' stage(t) shares visible
    asm volatile("" ::: "memory");       // no LDS reads hoist above barrier

    const char* sA = (const char*)(lds + (t & 3) * 32768);
    const char* sB = sA + 16384;
    // frag (mb, ks): 16B at ((mb*2+ks)*1024) + lane*16; rows mb*32+(l&31),
    // k = ks*16 + (lane>>5)*8 + e
    bf16x8_t a[4][2], b[2][2];
#pragma unroll
    for (int m = 0; m < 4; ++m)
#pragma unroll
      for (int ks = 0; ks < 2; ++ks)
        a[m][ks] = *(const bf16x8_t*)(sA + ((wr * 4 + m) * 2 + ks) * 1024 + lane * 16);
#pragma unroll
    for (int n = 0; n < 2; ++n)
#pragma unroll
      for (int ks = 0; ks < 2; ++ks)
        b[n][ks] = *(const bf16x8_t*)(sB + ((wc * 2 + n) * 2 + ks) * 1024 + lane * 16);
    __builtin_amdgcn_s_setprio(1);
#pragma unroll
    for (int ks = 0; ks < 2; ++ks)
#pragma unroll
      for (int m = 0; m < 4; ++m)
#pragma unroll
        for (int n = 0; n < 2; ++n)
          acc[m][n] = __builtin_amdgcn_mfma_f32_32x32x16_bf16(
              a[m][ks], b[n][ks], acc[m][n], 0, 0, 0);
    __builtin_amdgcn_s_setprio(0);
  }

  // ---- epilogue: relu(C + b1) * W2, reduce over cols, write partial ----
  // C/D map (verified): col = lane&31, row = (reg&3) + 8*(reg>>2) + 4*(lane>>5)
  float rs[4][16];
#pragma unroll
  for (int m = 0; m < 4; ++m)
#pragma unroll
    for (int rg = 0; rg < 16; ++rg) rs[m][rg] = 0.f;

#pragma unroll
  for (int n = 0; n < 2; ++n) {
    const int jg = n0 + wc * 64 + n * 32 + l5;
    const float w2v = W2[jg];
    const float b1v = b1[jg];
#pragma unroll
    for (int m = 0; m < 4; ++m)
#pragma unroll
      for (int rg = 0; rg < 16; ++rg) {
        float v = acc[m][n][rg] + b1v;
        rs[m][rg] += fmaxf(v, 0.f) * w2v;
      }
  }
  // reduce across the 32 lanes holding the same rows (xor<=16 stays in half)
#pragma unroll
  for (int m = 0; m < 4; ++m)
#pragma unroll
    for (int rg = 0; rg < 16; ++rg) {
      float v = rs[m][rg];
      v += __shfl_xor(v, 1);
      v += __shfl_xor(v, 2);
      v += __shfl_xor(v, 4);
      v += __shfl_xor(v, 8);
      v += __shfl_xor(v, 16);
      rs[m][rg] = v;
    }
  __syncthreads();                        // all frag reads done; alias lds
  float (*part_lds)[4] = (float(*)[4])lds;   // [256][4]
  if (l5 == 0) {
#pragma unroll
    for (int m = 0; m < 4; ++m)
#pragma unroll
      for (int rg = 0; rg < 16; ++rg) {
        const int row = wr * 128 + m * 32 + (rg & 3) + 8 * (rg >> 2) + 4 * hi;
        part_lds[row][wc] = rs[m][rg];
      }
  }
  __syncthreads();
  if (tid < 256) {
    const float sum = part_lds[tid][0] + part_lds[tid][1]
                    + part_lds[tid][2] + part_lds[tid][3];
    partial[(size_t)(m0 + tid) * NBLK + nt] = sum;
  }
}

// ---------------------------------------------------------------------------
// K2a: logits[i] = b2 + sum(partial[i][:]); flag near-threshold tokens
// ---------------------------------------------------------------------------
__global__ __launch_bounds__(256) void k2a_logits(
    const float* __restrict__ partial,
    const float* __restrict__ b2,
    float* __restrict__ logits,
    int* __restrict__ flaglist,
    int* __restrict__ flagcnt)
{
  const int i = blockIdx.x * 256 + threadIdx.x;   // 0..16383
  const float* pp = partial + (size_t)i * NBLK;
  float lg = b2[0];
#pragma unroll
  for (int j = 0; j < NBLK; ++j) lg += pp[j];
  logits[i] = lg;
  if (fabsf(lg) < MARGIN) {
    int s = atomicAdd(flagcnt, 1);
    if (s < MAXFLAG) flaglist[s] = i;
  }
}

// ---------------------------------------------------------------------------
// K2b: exact f32 recompute of flagged rows, split 8x by column group.
// grid (8 cg, 64 fslot); partials to fixpart[f][cg] (deterministic).
// ---------------------------------------------------------------------------
__global__ __launch_bounds__(256) void k2b_fixup(
    const float* __restrict__ hidden,
    const float* __restrict__ W1,
    const float* __restrict__ b1,
    const float* __restrict__ W2,
    const int* __restrict__ flaglist,
    const int* __restrict__ flagcnt,
    float* __restrict__ fixpart)         // [MAXFLAG][8]
{
  const int cnt = min(*flagcnt, MAXFLAG);
  const int cg = blockIdx.x;             // 0..7
  __shared__ float hrow[D_];
  __shared__ float red[256];
  const int tid = threadIdx.x;
  const int col = cg * 256 + tid;
  for (int f = blockIdx.y; f < cnt; f += 64) {
    const int i = flaglist[f];
    const float* h = hidden + (size_t)i * D_;
    __syncthreads();
    *(f32x4_t*)&hrow[tid * 4] = *(const f32x4_t*)&h[tid * 4];
    __syncthreads();
    float acc = 0.f;
#pragma unroll 8
    for (int k = 0; k < D_; ++k)
      acc = fmaf(hrow[k], W1[(size_t)k * H_ + col], acc);
    red[tid] = fmaxf(acc + b1[col], 0.f) * W2[col];
    __syncthreads();
    for (int st = 128; st > 0; st >>= 1) {
      if (tid < st) red[tid] += red[tid + st];
      __syncthreads();
    }
    if (tid == 0) fixpart[f * 8 + cg] = red[0];
  }
}

// ---------------------------------------------------------------------------
// K2b2: combine column-group partials -> corrected logits (deterministic)
// ---------------------------------------------------------------------------
__global__ __launch_bounds__(256) void k2b2_combine(
    const float* __restrict__ fixpart,
    const float* __restrict__ b2,
    const int* __restrict__ flaglist,
    const int* __restrict__ flagcnt,
    float* __restrict__ logits)
{
  const int cnt = min(*flagcnt, MAXFLAG);
  for (int f = threadIdx.x; f < cnt; f += 256) {
    float s = b2[0];
#pragma unroll
    for (int cg = 0; cg < 8; ++cg) s += fixpart[f * 8 + cg];
    logits[flaglist[f]] = s;
  }
}

// ---------------------------------------------------------------------------
// K2c: per-batch scan (lengths, hb bits, segment starts, masks, NLL)
// ---------------------------------------------------------------------------
__global__ __launch_bounds__(256) void k2c_scan(
    const float* __restrict__ logits,    // [8][2048]
    const float* __restrict__ mask,      // [8][2048]
    const float* __restrict__ target,    // [8]
    float* __restrict__ outmask,         // [8][2048]
    int*   __restrict__ seg,             // [8][2050]
    float* __restrict__ hdr)             // [8][4]
{
  const int b = blockIdx.x, tid = threadIdx.x;
  __shared__ float redf[256];
  __shared__ int tsum[257];
  __shared__ unsigned char hbs[L_];

  float lm = 0.f;
#pragma unroll
  for (int e = 0; e < 8; ++e) lm += mask[b * L_ + tid * 8 + e];
  redf[tid] = lm;
  __syncthreads();
  for (int s = 128; s > 0; s >>= 1) {
    if (tid < s) redf[tid] += redf[tid + s];
    __syncthreads();
  }
  const int length = (int)(redf[0] + 0.5f);

  int hloc[8];
  int lsum = 0;
#pragma unroll
  for (int e = 0; e < 8; ++e) {
    const int t = tid * 8 + e;
    const float lg = logits[b * L_ + t];
    int hb = (lg > 0.f) && (t < length);
    if (length < L_ && t == length - 1) hb = 1;
    hloc[e] = hb;
    hbs[t] = (unsigned char)hb;
    lsum += hb;
  }
  tsum[tid] = lsum;
  __syncthreads();
  if (tid == 0) {
    int run = 0;
    for (int i = 0; i < 256; ++i) { int v = tsum[i]; tsum[i] = run; run += v; }
    tsum[256] = run;
  }
  __syncthreads();
  const int ktot = tsum[256];

  int pre = tsum[tid];
  for (int e = 0; e < 8; ++e) {
    const int t = tid * 8 + e;
    if (t < length) {
      const bool st = (t == 0) || hbs[t - 1];
      if (st) seg[b * 2050 + pre] = t;
    }
    pre += hloc[e];
  }

#pragma unroll
  for (int e = 0; e < 8; ++e) {
    const int t = tid * 8 + e;
    outmask[b * L_ + t] = (t < ktot) ? 1.f : 0.f;
  }

  __syncthreads();
  if (tid == 0) {
    const int maxseg = ktot - (length > 0 ? (int)hbs[length - 1] : 0);
    seg[b * 2050 + maxseg + 1] = length;
    const float n = (float)length, k = (float)ktot;
    float p = target[b] / fmaxf(n, 1.f);
    p = fminf(fmaxf(p, 1e-6f), 1.f - 1e-6f);
    const float lp = lgammaf(n + 1.f) - lgammaf(k + 1.f) - lgammaf(n - k + 1.f)
                   + k * logf(p) + (n - k) * log1pf(-p);
    hdr[b * 4 + 0] = n;
    hdr[b * 4 + 1] = k;
    hdr[b * 4 + 2] = (float)maxseg;
    hdr[b * 4 + 3] = -lp;
  }
}

// ---------------------------------------------------------------------------
// K4b: pooled[b][s][:] = mean(hidden[b][st:en][:]) + PE[s][:]
// segment mean = edge rows + full 32-token chunk sums. Block 0 also emits
// the three scalars.
// ---------------------------------------------------------------------------
__global__ __launch_bounds__(256) void k4b_pool(
    const float* __restrict__ hidden,
    const float* __restrict__ chunkSum,
    const int*   __restrict__ seg,
    const float* __restrict__ hdr,
    float* __restrict__ pooled,
    float* __restrict__ out3)
{
  const int bid = blockIdx.x;
  const int b = bid >> 11, s = bid & 2047;
  const int tid = threadIdx.x;
  if (bid == 0 && tid == 0) {
    float s_lp = 0.f, s_k = 0.f, s_n = 0.f;
    for (int i = 0; i < B_; ++i) {
      s_n  += hdr[i * 4 + 0];
      s_k  += hdr[i * 4 + 1];
      s_lp += hdr[i * 4 + 3];
    }
    out3[0] = 10.f * (s_lp * 0.125f);
    out3[1] = s_k;
    out3[2] = s_n;
  }
  const int maxseg = (int)hdr[b * 4 + 2];

  float a0 = 0.f, a1 = 0.f, a2 = 0.f, a3 = 0.f;
  if (s <= maxseg) {
    const int st = seg[b * 2050 + s];
    const int en = seg[b * 2050 + s + 1];
    const float* hrow = hidden + (size_t)(b * L_) * D_ + tid * 4;
    const float* crow = chunkSum + (size_t)(b * NCH) * D_ + tid * 4;
    const int cs = (st + CHK - 1) / CHK;
    const int ce = en / CHK;
    if (cs >= ce) {
      for (int t = st; t < en; ++t) {
        const f32x4_t v = *(const f32x4_t*)(hrow + (size_t)t * D_);
        a0 += v.x; a1 += v.y; a2 += v.z; a3 += v.w;
      }
    } else {
      for (int t = st; t < cs * CHK; ++t) {
        const f32x4_t v = *(const f32x4_t*)(hrow + (size_t)t * D_);
        a0 += v.x; a1 += v.y; a2 += v.z; a3 += v.w;
      }
#pragma unroll 4
      for (int c = cs; c < ce; ++c) {
        const f32x4_t v = *(const f32x4_t*)(crow + (size_t)c * D_);
        a0 += v.x; a1 += v.y; a2 += v.z; a3 += v.w;
      }
      for (int t = ce * CHK; t < en; ++t) {
        const f32x4_t v = *(const f32x4_t*)(hrow + (size_t)t * D_);
        a0 += v.x; a1 += v.y; a2 += v.z; a3 += v.w;
      }
    }
    const float cnt = (float)(en - st);
    const float inv = 1.f / (cnt + 1e-9f);
    a0 *= inv; a1 *= inv; a2 *= inv; a3 *= inv;
  }
  // PE: ang = s * 10000^(-e) = s * exp2f(-e * log2(10000))
  const float L2_10K = 13.287712379549449f;
  const float e0 = (float)(4 * tid)     * (1.f / 1024.f);
  const float e1 = (float)(4 * tid + 2) * (1.f / 1024.f);
  const float ang0 = (float)s * exp2f(-e0 * L2_10K);
  const float ang1 = (float)s * exp2f(-e1 * L2_10K);
  float s0, c0, s1, c1;
  sincosf(ang0, &s0, &c0);
  sincosf(ang1, &s1, &c1);
  f32x4_t o;
  o.x = a0 + s0; o.y = a1 + c0; o.z = a2 + s1; o.w = a3 + c1;
  *(f32x4_t*)(pooled + ((size_t)(b * L_ + s)) * D_ + tid * 4) = o;
}

// ---------------------------------------------------------------------------
extern "C" void kernel_launch(void* const* d_in, const int* in_sizes, int n_in,
                              void* d_out, int out_size, void* d_ws, size_t ws_size,
                              hipStream_t stream)
{
  (void)in_sizes; (void)n_in; (void)out_size; (void)ws_size;
  const float* hidden = (const float*)d_in[0];
  const float* amask  = (const float*)d_in[1];
  const float* target = (const float*)d_in[2];
  const float* W1     = (const float*)d_in[3];
  const float* b1     = (const float*)d_in[4];
  const float* W2     = (const float*)d_in[5];
  const float* b2     = (const float*)d_in[6];

  float* out     = (float*)d_out;
  float* pooled  = out;                       // 16777216 floats (written LAST)
  float* out3    = out + 16777216;
  float* outmask = out + 16777219;

  // Abf (32MB) + Bbf (4MB) live inside the pooled output region as scratch;
  // k4b fully overwrites pooled afterwards.
  bf16_t* Abf = (bf16_t*)out;                       // 32 MB
  bf16_t* Bbf = (bf16_t*)(out + 8388608);           // 4 MB at byte offset 32MB

  char* ws = (char*)d_ws;
  float* partial  = (float*)ws;                      ws += (size_t)16384 * NBLK * 4;  // 512 KB
  int*   seg      = (int*)ws;                        ws += (size_t)B_ * 2050 * 4;
  float* hdr      = (float*)ws;                      ws += (size_t)B_ * 4 * 4;
  float* logits   = (float*)ws;                      ws += (size_t)B_ * L_ * 4;       // 64 KB
  int*   flaglist = (int*)ws;                        ws += (size_t)MAXFLAG * 4;
  int*   flagcnt  = (int*)ws;                        ws += 256;
  float* fixpart  = (float*)ws;                      ws += (size_t)MAXFLAG * 8 * 4;   // 32 KB
  float* chunkSum = (float*)ws;                      // 2 MB

  k0a_packA<<<dim3(32, 64), dim3(256), 0, stream>>>(hidden, Abf, chunkSum);
  k0b_packB<<<dim3(32, 8), dim3(256), 0, stream>>>(W1, Bbf, flagcnt);
  k1_gemm<<<dim3(512), dim3(512), 131072, stream>>>(Abf, Bbf, b1, W2, partial);
  k2a_logits<<<dim3(64), dim3(256), 0, stream>>>(partial, b2, logits, flaglist, flagcnt);
  k2b_fixup<<<dim3(8, 64), dim3(256), 0, stream>>>(hidden, W1, b1, W2,
                                                   flaglist, flagcnt, fixpart);
  k2b2_combine<<<dim3(1), dim3(256), 0, stream>>>(fixpart, b2, flaglist, flagcnt, logits);
  k2c_scan<<<dim3(8), dim3(256), 0, stream>>>(logits, amask, target, outmask, seg, hdr);
  k4b_pool<<<dim3(16384), dim3(256), 0, stream>>>(hidden, chunkSum, seg, hdr, pooled, out3);
}

// Round 7
// 127.140 us; speedup vs baseline: 5.8579x; 1.1031x over previous
//
#include <hip/hip_runtime.h>
#include <math.h>

#define B_   8
#define L_   2048
#define D_   1024
#define H_   2048
#define NBLK 8             // H_/256 N-tiles in the GEMM
#define CHK  32            // tokens per chunk in pooling pre-pass
#define NCH  (L_ / CHK)    // 64 chunks per batch item
#define BK   32
#define NK   (D_ / BK)     // 32 K-steps
#define MARGIN  0.05f      // |logit| below this -> exact f32 recompute
#define MAXFLAG 1024

typedef __bf16 bf16_t;
typedef bf16_t bf16x8_t __attribute__((ext_vector_type(8)));
typedef float  f32x4_t  __attribute__((ext_vector_type(4)));

// Swizzled tile images: tile = 256 rows x BK(32) k-elems bf16 = 16KB.
// Row r holds 4 chunks of 16B (8 bf16); k-group g stored at physical chunk
// g ^ ((r>>1)&3)  -> ds_read_b128 spans all 8 bank-quads over 8 rows (2-way).
#define TILE_BYTES 16384

// ---------------------------------------------------------------------------
// K0a (fused): hidden f32 -> Abf bf16 swizzled tiles AND 32-token chunk sums
// grid (kt=32, mt=64), 256 threads; thread r owns row r of the tile.
// ---------------------------------------------------------------------------
__global__ __launch_bounds__(256) void k0a_packA(
    const float* __restrict__ A,      // [16384][1024]
    bf16_t* __restrict__ Abf,         // [64 mt][32 kt] tiles of 16KB
    float* __restrict__ chunkSum)     // [8][NCH][1024]
{
  __shared__ float scratch[256][33];
  const int kt = blockIdx.x;   // 0..31
  const int mt = blockIdx.y;   // 0..63
  const int r  = threadIdx.x;  // 0..255
  const float* src = A + (size_t)(mt * 256 + r) * D_ + kt * BK;
  float v[32];
#pragma unroll
  for (int q = 0; q < 8; ++q) {
    f32x4_t x = *(const f32x4_t*)(src + q * 4);
    v[q*4] = x.x; v[q*4+1] = x.y; v[q*4+2] = x.z; v[q*4+3] = x.w;
  }
  char* dst = (char*)Abf + ((size_t)(mt * 32 + kt)) * TILE_BYTES + r * 64;
#pragma unroll
  for (int g = 0; g < 4; ++g) {
    bf16x8_t o;
#pragma unroll
    for (int e = 0; e < 8; ++e) o[e] = (bf16_t)v[g * 8 + e];
    *(bf16x8_t*)(dst + ((g ^ ((r >> 1) & 3)) << 4)) = o;
  }
  // chunk sums: tile spans 256 tokens = 8 chunks of 32
#pragma unroll
  for (int q = 0; q < 8; ++q)
    *(f32x4_t*)&scratch[r][q * 4] = *(const f32x4_t*)&v[q * 4];
  __syncthreads();
  const int ch = r >> 5, j = r & 31;
  float s = 0.f;
#pragma unroll
  for (int q = 0; q < 32; ++q) s += scratch[ch * 32 + q][j];
  const int b  = mt >> 3;
  const int cg = (mt & 7) * 8 + ch;
  chunkSum[((size_t)(b * NCH + cg)) * D_ + kt * BK + j] = s;
}

// ---------------------------------------------------------------------------
// K0b: W1 f32 -> Bbf bf16 swizzled tiles; also zeroes flagcnt
// ---------------------------------------------------------------------------
__global__ __launch_bounds__(256) void k0b_packB(
    const float* __restrict__ W1,     // [1024][2048]
    bf16_t* __restrict__ Bbf,         // [8 nt][32 kt] tiles of 16KB
    int* __restrict__ flagcnt)
{
  const int kt = blockIdx.x;   // 0..31
  const int nt = blockIdx.y;   // 0..7
  const int c  = threadIdx.x;  // 0..255
  if (kt == 0 && nt == 0 && c == 0) *flagcnt = 0;
  const float* src = W1 + (size_t)(kt * BK) * H_ + nt * 256 + c;
  float v[32];
#pragma unroll
  for (int j = 0; j < 32; ++j) v[j] = src[(size_t)j * H_];
  char* dst = (char*)Bbf + ((size_t)(nt * 32 + kt)) * TILE_BYTES + c * 64;
#pragma unroll
  for (int g = 0; g < 4; ++g) {
    bf16x8_t o;
#pragma unroll
    for (int e = 0; e < 8; ++e) o[e] = (bf16_t)v[g * 8 + e];
    *(bf16x8_t*)(dst + ((g ^ ((c >> 1) & 3)) << 4)) = o;
  }
}

// ---------------------------------------------------------------------------
// K1: bf16 GEMM 256x256 tile, BK=32, 8 waves (2Mx4N, wave tile 128x64).
// 4-way LDS ring (4 x 32KB), depth-2 prefetch via global_load_lds(16B),
// ONE raw s_barrier per K-step, counted s_waitcnt vmcnt(8) (never 0 in loop).
// Epilogue: relu(C + b1) . W2 row-reduce -> partial[m][nt].
// (Round-4 measured best: 66.8 us, 1028 TF, MfmaUtil 42%, 0 conflicts.)
// ---------------------------------------------------------------------------
__global__ __launch_bounds__(512, 2) void k1_gemm(
    const bf16_t* __restrict__ Abf,
    const bf16_t* __restrict__ Bbf,
    const float* __restrict__ b1,
    const float* __restrict__ W2,
    float* __restrict__ partial)    // [16384][NBLK]
{
  extern __shared__ __align__(16) unsigned char lds[];   // 131072 bytes

  const int tid  = threadIdx.x;           // 0..511
  // XCD-bijective swizzle (512 blocks % 8 == 0)
  const int wg   = (blockIdx.x & 7) * 64 + (blockIdx.x >> 3);
  const int mt   = wg >> 3;               // 0..63
  const int nt   = wg & 7;                // 0..7
  const int m0   = mt * 256;
  const int n0   = nt * 256;
  const int lane = tid & 63;
  const int wave = tid >> 6;              // 0..7
  const int wr = wave >> 2, wc = wave & 3;
  const int lr = lane & 15, lk = lane >> 4;

  const char* aT = (const char*)Abf + ((size_t)mt * 32) * TILE_BYTES;
  const char* bT = (const char*)Bbf + ((size_t)nt * 32) * TILE_BYTES;

  f32x4_t acc[8][4];
#pragma unroll
  for (int m = 0; m < 8; ++m)
#pragma unroll
    for (int n = 0; n < 4; ++n)
      acc[m][n] = (f32x4_t){0.f, 0.f, 0.f, 0.f};

  // stage K-step t into ring buffer buf: A tile 16KB then B tile 16KB
  auto stage = [&](int t, int buf) {
    const char* ga = aT + (size_t)t * TILE_BYTES;
    const char* gb = bT + (size_t)t * TILE_BYTES;
    unsigned char* lb = lds + buf * 32768;
#pragma unroll
    for (int j = 0; j < 4; ++j) {
      const int i = j * 512 + tid;        // 0..2047 16B-chunks
      const char* g = (j < 2) ? ga + i * 16 : gb + (i - 1024) * 16;
      __builtin_amdgcn_global_load_lds(
          (const __attribute__((address_space(1))) void*)g,
          (__attribute__((address_space(3))) void*)(lb + i * 16),
          16, 0, 0);
    }
  };

  stage(0, 0);
  stage(1, 1);
  for (int t = 0; t < NK; ++t) {
    if (t + 2 < NK) {
      stage(t + 2, (t + 2) & 3);
      asm volatile("s_waitcnt vmcnt(8)" ::: "memory");   // stage(t) landed
    } else if (t + 1 < NK) {
      asm volatile("s_waitcnt vmcnt(4)" ::: "memory");
    } else {
      asm volatile("s_waitcnt vmcnt(0)" ::: "memory");
    }
    __builtin_amdgcn_s_barrier();        // all waves' stage(t) shares visible
    asm volatile("" ::: "memory");       // no LDS reads hoist above barrier

    const char* sA = (const char*)(lds + (t & 3) * 32768);
    const char* sB = sA + 16384;
    bf16x8_t a[8], b[4];
#pragma unroll
    for (int m = 0; m < 8; ++m) {
      const int r = wr * 128 + m * 16 + lr;
      a[m] = *(const bf16x8_t*)(sA + r * 64 + ((lk ^ ((r >> 1) & 3)) << 4));
    }
#pragma unroll
    for (int n = 0; n < 4; ++n) {
      const int c = wc * 64 + n * 16 + lr;
      b[n] = *(const bf16x8_t*)(sB + c * 64 + ((lk ^ ((c >> 1) & 3)) << 4));
    }
    __builtin_amdgcn_s_setprio(1);
#pragma unroll
    for (int m = 0; m < 8; ++m)
#pragma unroll
      for (int n = 0; n < 4; ++n)
        acc[m][n] = __builtin_amdgcn_mfma_f32_16x16x32_bf16(a[m], b[n], acc[m][n], 0, 0, 0);
    __builtin_amdgcn_s_setprio(0);
  }

  // ---- epilogue: relu(C + b1) * W2, reduce over cols, write partial ----
  float rs[8][4];
#pragma unroll
  for (int m = 0; m < 8; ++m)
#pragma unroll
    for (int rg = 0; rg < 4; ++rg) rs[m][rg] = 0.f;

#pragma unroll
  for (int n = 0; n < 4; ++n) {
    const int jg = n0 + wc * 64 + n * 16 + lr;   // C/D: col = lane&15
    const float w2v = W2[jg];
    const float b1v = b1[jg];
#pragma unroll
    for (int m = 0; m < 8; ++m)
#pragma unroll
      for (int rg = 0; rg < 4; ++rg) {
        float v = acc[m][n][rg] + b1v;
        rs[m][rg] += fmaxf(v, 0.f) * w2v;
      }
  }
#pragma unroll
  for (int m = 0; m < 8; ++m)
#pragma unroll
    for (int rg = 0; rg < 4; ++rg) {
      float v = rs[m][rg];
      v += __shfl_xor(v, 1);
      v += __shfl_xor(v, 2);
      v += __shfl_xor(v, 4);
      v += __shfl_xor(v, 8);
      rs[m][rg] = v;                      // col-sum of this wave's 64-col slab
    }
  __syncthreads();                        // all frag reads done; alias lds
  float (*part_lds)[4] = (float(*)[4])lds;   // [256][4]
  if (lr == 0) {
#pragma unroll
    for (int m = 0; m < 8; ++m)
#pragma unroll
      for (int rg = 0; rg < 4; ++rg)
        part_lds[wr * 128 + m * 16 + lk * 4 + rg][wc] = rs[m][rg];
  }
  __syncthreads();
  if (tid < 256) {
    const float sum = part_lds[tid][0] + part_lds[tid][1]
                    + part_lds[tid][2] + part_lds[tid][3];
    partial[(size_t)(m0 + tid) * NBLK + nt] = sum;
  }
}

// ---------------------------------------------------------------------------
// K2a: logits[i] = b2 + sum(partial[i][:]); flag near-threshold tokens
// ---------------------------------------------------------------------------
__global__ __launch_bounds__(256) void k2a_logits(
    const float* __restrict__ partial,
    const float* __restrict__ b2,
    float* __restrict__ logits,
    int* __restrict__ flaglist,
    int* __restrict__ flagcnt)
{
  const int i = blockIdx.x * 256 + threadIdx.x;   // 0..16383
  const float* pp = partial + (size_t)i * NBLK;
  float lg = b2[0];
#pragma unroll
  for (int j = 0; j < NBLK; ++j) lg += pp[j];
  logits[i] = lg;
  if (fabsf(lg) < MARGIN) {
    int s = atomicAdd(flagcnt, 1);
    if (s < MAXFLAG) flaglist[s] = i;
  }
}

// ---------------------------------------------------------------------------
// K2b: exact f32 recompute of flagged rows, split 8x by column group.
// grid (8 cg, 64 fslot); partials to fixpart[f][cg] (deterministic).
// ---------------------------------------------------------------------------
__global__ __launch_bounds__(256) void k2b_fixup(
    const float* __restrict__ hidden,
    const float* __restrict__ W1,
    const float* __restrict__ b1,
    const float* __restrict__ W2,
    const int* __restrict__ flaglist,
    const int* __restrict__ flagcnt,
    float* __restrict__ fixpart)         // [MAXFLAG][8]
{
  const int cnt = min(*flagcnt, MAXFLAG);
  const int cg = blockIdx.x;             // 0..7
  __shared__ float hrow[D_];
  __shared__ float red[256];
  const int tid = threadIdx.x;
  const int col = cg * 256 + tid;
  for (int f = blockIdx.y; f < cnt; f += 64) {
    const int i = flaglist[f];
    const float* h = hidden + (size_t)i * D_;
    __syncthreads();
    *(f32x4_t*)&hrow[tid * 4] = *(const f32x4_t*)&h[tid * 4];
    __syncthreads();
    float acc = 0.f;
#pragma unroll 8
    for (int k = 0; k < D_; ++k)
      acc = fmaf(hrow[k], W1[(size_t)k * H_ + col], acc);
    red[tid] = fmaxf(acc + b1[col], 0.f) * W2[col];
    __syncthreads();
    for (int st = 128; st > 0; st >>= 1) {
      if (tid < st) red[tid] += red[tid + st];
      __syncthreads();
    }
    if (tid == 0) fixpart[f * 8 + cg] = red[0];
  }
}

// ---------------------------------------------------------------------------
// K2c: per-batch scan. Prologue applies fixup combine for this batch's
// flagged tokens; then lengths, hb bits, parallel prefix scan, segment
// starts, shortened mask, binomial NLL.
// ---------------------------------------------------------------------------
__global__ __launch_bounds__(256) void k2c_scan(
    float* __restrict__ logits,          // [8][2048] (fixed in-place)
    const float* __restrict__ mask,      // [8][2048]
    const float* __restrict__ target,    // [8]
    const float* __restrict__ b2,
    const float* __restrict__ fixpart,   // [MAXFLAG][8]
    const int* __restrict__ flaglist,
    const int* __restrict__ flagcnt,
    float* __restrict__ outmask,         // [8][2048]
    int*   __restrict__ seg,             // [8][2050]
    float* __restrict__ hdr)             // [8][4]
{
  const int b = blockIdx.x, tid = threadIdx.x;
  __shared__ float redf[256];
  __shared__ int tsum[256];
  __shared__ unsigned char hbs[L_];

  // fix-combine for this batch's flagged tokens (exact f32 logits)
  const int cnt = min(*flagcnt, MAXFLAG);
  for (int f = tid; f < cnt; f += 256) {
    const int i = flaglist[f];
    if ((i >> 11) == b) {
      float s = b2[0];
#pragma unroll
      for (int cg = 0; cg < 8; ++cg) s += fixpart[f * 8 + cg];
      logits[i] = s;
    }
  }
  // length (tree reduce); the first barrier also orders the fixup writes
  float lm = 0.f;
#pragma unroll
  for (int e = 0; e < 8; ++e) lm += mask[b * L_ + tid * 8 + e];
  redf[tid] = lm;
  __syncthreads();
  for (int s = 128; s > 0; s >>= 1) {
    if (tid < s) redf[tid] += redf[tid + s];
    __syncthreads();
  }
  const int length = (int)(redf[0] + 0.5f);

  int hloc[8];
  int lsum = 0;
#pragma unroll
  for (int e = 0; e < 8; ++e) {
    const int t = tid * 8 + e;
    const float lg = logits[b * L_ + t];
    int hb = (lg > 0.f) && (t < length);
    if (length < L_ && t == length - 1) hb = 1;
    hloc[e] = hb;
    hbs[t] = (unsigned char)hb;
    lsum += hb;
  }
  // parallel inclusive scan (Hillis-Steele) over per-thread sums
  tsum[tid] = lsum;
  __syncthreads();
  for (int off = 1; off < 256; off <<= 1) {
    int v = tsum[tid];
    int add = (tid >= off) ? tsum[tid - off] : 0;
    __syncthreads();
    tsum[tid] = v + add;
    __syncthreads();
  }
  const int ktot = tsum[255];

  int pre = tsum[tid] - lsum;            // exclusive prefix
  for (int e = 0; e < 8; ++e) {
    const int t = tid * 8 + e;
    if (t < length) {
      const bool st = (t == 0) || hbs[t - 1];
      if (st) seg[b * 2050 + pre] = t;
    }
    pre += hloc[e];
  }

#pragma unroll
  for (int e = 0; e < 8; ++e) {
    const int t = tid * 8 + e;
    outmask[b * L_ + t] = (t < ktot) ? 1.f : 0.f;
  }

  __syncthreads();
  if (tid == 0) {
    const int maxseg = ktot - (length > 0 ? (int)hbs[length - 1] : 0);
    seg[b * 2050 + maxseg + 1] = length;
    const float n = (float)length, k = (float)ktot;
    float p = target[b] / fmaxf(n, 1.f);
    p = fminf(fmaxf(p, 1e-6f), 1.f - 1e-6f);
    const float lp = lgammaf(n + 1.f) - lgammaf(k + 1.f) - lgammaf(n - k + 1.f)
                   + k * logf(p) + (n - k) * log1pf(-p);
    hdr[b * 4 + 0] = n;
    hdr[b * 4 + 1] = k;
    hdr[b * 4 + 2] = (float)maxseg;
    hdr[b * 4 + 3] = -lp;
  }
}

// ---------------------------------------------------------------------------
// K4b: pooled[b][s][:] = mean(hidden[b][st:en][:]) + PE[s][:]
// segment mean = edge rows + full 32-token chunk sums. Block 0 also emits
// the three scalars.
// ---------------------------------------------------------------------------
__global__ __launch_bounds__(256) void k4b_pool(
    const float* __restrict__ hidden,
    const float* __restrict__ chunkSum,
    const int*   __restrict__ seg,
    const float* __restrict__ hdr,
    float* __restrict__ pooled,
    float* __restrict__ out3)
{
  const int bid = blockIdx.x;
  const int b = bid >> 11, s = bid & 2047;
  const int tid = threadIdx.x;
  if (bid == 0 && tid == 0) {
    float s_lp = 0.f, s_k = 0.f, s_n = 0.f;
    for (int i = 0; i < B_; ++i) {
      s_n  += hdr[i * 4 + 0];
      s_k  += hdr[i * 4 + 1];
      s_lp += hdr[i * 4 + 3];
    }
    out3[0] = 10.f * (s_lp * 0.125f);
    out3[1] = s_k;
    out3[2] = s_n;
  }
  const int maxseg = (int)hdr[b * 4 + 2];

  float a0 = 0.f, a1 = 0.f, a2 = 0.f, a3 = 0.f;
  if (s <= maxseg) {
    const int st = seg[b * 2050 + s];
    const int en = seg[b * 2050 + s + 1];
    const float* hrow = hidden + (size_t)(b * L_) * D_ + tid * 4;
    const float* crow = chunkSum + (size_t)(b * NCH) * D_ + tid * 4;
    const int cs = (st + CHK - 1) / CHK;
    const int ce = en / CHK;
    if (cs >= ce) {
      for (int t = st; t < en; ++t) {
        const f32x4_t v = *(const f32x4_t*)(hrow + (size_t)t * D_);
        a0 += v.x; a1 += v.y; a2 += v.z; a3 += v.w;
      }
    } else {
      for (int t = st; t < cs * CHK; ++t) {
        const f32x4_t v = *(const f32x4_t*)(hrow + (size_t)t * D_);
        a0 += v.x; a1 += v.y; a2 += v.z; a3 += v.w;
      }
#pragma unroll 4
      for (int c = cs; c < ce; ++c) {
        const f32x4_t v = *(const f32x4_t*)(crow + (size_t)c * D_);
        a0 += v.x; a1 += v.y; a2 += v.z; a3 += v.w;
      }
      for (int t = ce * CHK; t < en; ++t) {
        const f32x4_t v = *(const f32x4_t*)(hrow + (size_t)t * D_);
        a0 += v.x; a1 += v.y; a2 += v.z; a3 += v.w;
      }
    }
    const float cnt = (float)(en - st);
    const float inv = 1.f / (cnt + 1e-9f);
    a0 *= inv; a1 *= inv; a2 *= inv; a3 *= inv;
  }
  // PE: ang = s * 10000^(-e) = s * exp2(-e * log2(10000)); fast HW sincos
  const float L2_10K = 13.287712379549449f;
  const float e0 = (float)(4 * tid)     * (1.f / 1024.f);
  const float e1 = (float)(4 * tid + 2) * (1.f / 1024.f);
  const float ang0 = (float)s * exp2f(-e0 * L2_10K);
  const float ang1 = (float)s * exp2f(-e1 * L2_10K);
  float s0, c0, s1, c1;
  __sincosf(ang0, &s0, &c0);
  __sincosf(ang1, &s1, &c1);
  f32x4_t o;
  o.x = a0 + s0; o.y = a1 + c0; o.z = a2 + s1; o.w = a3 + c1;
  *(f32x4_t*)(pooled + ((size_t)(b * L_ + s)) * D_ + tid * 4) = o;
}

// ---------------------------------------------------------------------------
extern "C" void kernel_launch(void* const* d_in, const int* in_sizes, int n_in,
                              void* d_out, int out_size, void* d_ws, size_t ws_size,
                              hipStream_t stream)
{
  (void)in_sizes; (void)n_in; (void)out_size; (void)ws_size;
  const float* hidden = (const float*)d_in[0];
  const float* amask  = (const float*)d_in[1];
  const float* target = (const float*)d_in[2];
  const float* W1     = (const float*)d_in[3];
  const float* b1     = (const float*)d_in[4];
  const float* W2     = (const float*)d_in[5];
  const float* b2     = (const float*)d_in[6];

  float* out     = (float*)d_out;
  float* pooled  = out;                       // 16777216 floats (written LAST)
  float* out3    = out + 16777216;
  float* outmask = out + 16777219;

  // Abf (32MB) + Bbf (4MB) live inside the pooled output region as scratch;
  // k4b fully overwrites pooled afterwards.
  bf16_t* Abf = (bf16_t*)out;                       // 32 MB
  bf16_t* Bbf = (bf16_t*)(out + 8388608);           // 4 MB at byte offset 32MB

  char* ws = (char*)d_ws;
  float* partial  = (float*)ws;                      ws += (size_t)16384 * NBLK * 4;  // 512 KB
  int*   seg      = (int*)ws;                        ws += (size_t)B_ * 2050 * 4;
  float* hdr      = (float*)ws;                      ws += (size_t)B_ * 4 * 4;
  float* logits   = (float*)ws;                      ws += (size_t)B_ * L_ * 4;       // 64 KB
  int*   flaglist = (int*)ws;                        ws += (size_t)MAXFLAG * 4;
  int*   flagcnt  = (int*)ws;                        ws += 256;
  float* fixpart  = (float*)ws;                      ws += (size_t)MAXFLAG * 8 * 4;   // 32 KB
  float* chunkSum = (float*)ws;                      // 2 MB

  k0a_packA<<<dim3(32, 64), dim3(256), 0, stream>>>(hidden, Abf, chunkSum);
  k0b_packB<<<dim3(32, 8), dim3(256), 0, stream>>>(W1, Bbf, flagcnt);
  k1_gemm<<<dim3(512), dim3(512), 131072, stream>>>(Abf, Bbf, b1, W2, partial);
  k2a_logits<<<dim3(64), dim3(256), 0, stream>>>(partial, b2, logits, flaglist, flagcnt);
  k2b_fixup<<<dim3(8, 64), dim3(256), 0, stream>>>(hidden, W1, b1, W2,
                                                   flaglist, flagcnt, fixpart);
  k2c_scan<<<dim3(8), dim3(256), 0, stream>>>(logits, amask, target, b2, fixpart,
                                              flaglist, flagcnt, outmask, seg, hdr);
  k4b_pool<<<dim3(16384), dim3(256), 0, stream>>>(hidden, chunkSum, seg, hdr, pooled, out3);
}